// Round 3
// baseline (488.116 us; speedup 1.0000x reference)
//
#include <hip/hip_runtime.h>
#include <hip/hip_bf16.h>

#define DI __device__ __forceinline__

typedef __bf16 bf16x8 __attribute__((ext_vector_type(8)));
typedef float f32x4 __attribute__((ext_vector_type(4)));

constexpr float SCALE_Q = 0.17677669529663687f; // 32^-0.5

// workspace byte offsets
constexpr int WQKV_OFF = 0;       // 27648 bf16 = 55296 B  (18 n-tiles x 3 k-iters x 64 lanes x 8)
constexpr int WVLO_OFF = 55296;   //  9216 bf16 = 18432 B  (Wv lo-part fragments)
constexpr int WPRJ_OFF = 73728;   //  9216 bf16 = 18432 B
constexpr int BIAS_OFF = 92160;   //   384 f32  = 1536 B   ([k 0:96][v 96:192][q 192:288][proj 288:384])
constexpr int RPE_OFF  = 93696;   // 12288 bf16 = 24576 B  (rpe2[3][64 row][16 l15][4 g], col=g*16+l15)
// total 118272 B

DI unsigned int f2b(float x) {  // float -> bf16 bits, RNE (software; prepack only)
  union { float f; unsigned int u; } v; v.f = x;
  return (v.u + 0x7fffu + ((v.u >> 16) & 1u)) >> 16;
}
DI unsigned short f2bh(float x) { // float -> bf16 bits via HW cvt (RNE)
  union { __bf16 b; unsigned short u; } v;
  v.b = (__bf16)x;
  return v.u;
}
DI float b2f(unsigned int u) {
  union { unsigned int u; float f; } v; v.u = u << 16;
  return v.f;
}
DI int sw192(int row, int bytecol) { return (row * 192 + bytecol) ^ ((row & 7) << 4); }
DI int sw384(int row, int bytecol) { return (row * 384 + bytecol) ^ ((row & 7) << 4); }

// ---------------------------------------------------------------------------
// Prepack: fragment-ordered bf16 weights (+Wv lo split), biases, gathered RPE.
// B-fragment layout for mfma_f32_16x16x32_bf16: lane l, elem j holds
// B[k = kt*32 + (l>>4)*8 + j][n = nt*16 + (l&15)].
// ---------------------------------------------------------------------------
__global__ void prepack_kernel(const float* __restrict__ qkv_w_a,
                               const float* __restrict__ qkv_b_a,
                               const float* __restrict__ qkv_w_b,
                               const float* __restrict__ qkv_b_b,
                               const float* __restrict__ rpe_table,
                               const float* __restrict__ proj_w,
                               const float* __restrict__ proj_b,
                               const int* __restrict__ rpe_index,
                               unsigned char* __restrict__ ws)
{
  unsigned short* wqkv = (unsigned short*)(ws + WQKV_OFF);
  unsigned short* wvlo = (unsigned short*)(ws + WVLO_OFF);
  unsigned short* wprj = (unsigned short*)(ws + WPRJ_OFF);
  float* bias          = (float*)(ws + BIAS_OFF);
  unsigned short* rpe  = (unsigned short*)(ws + RPE_OFF);

  const int total = 27648 + 9216 + 9216 + 384 + 12288;
  for (int idx = blockIdx.x * blockDim.x + threadIdx.x; idx < total;
       idx += gridDim.x * blockDim.x) {
    int i = idx;
    if (i < 27648) { // [Wk | Wv_hi | Wq*scale] fragments
      const int j = i & 7, lane = (i >> 3) & 63, t = i >> 9;
      const int kt = t % 3, nt = t / 3;
      const int k = kt * 32 + (lane >> 4) * 8 + j, c = lane & 15;
      float v;
      if (nt < 12) v = qkv_w_a[k * 288 + 96 + nt * 16 + c];      // Wk then Wv (cols 96..287)
      else         v = qkv_w_b[k * 288 + (nt - 12) * 16 + c] * SCALE_Q;
      wqkv[i] = (unsigned short)f2b(v);
    } else if ((i -= 27648) < 9216) { // Wv lo-part
      const int j = i & 7, lane = (i >> 3) & 63, t = i >> 9;
      const int kt = t % 3, vnt = t / 3;
      const int k = kt * 32 + (lane >> 4) * 8 + j, c = lane & 15;
      const float full = qkv_w_a[k * 288 + 192 + vnt * 16 + c];
      const unsigned int hi = f2b(full);
      wvlo[i] = (unsigned short)f2b(full - b2f(hi));
    } else if ((i -= 9216) < 9216) { // proj_w
      const int j = i & 7, lane = (i >> 3) & 63, t = i >> 9;
      const int kt = t % 3, nt = t / 3;
      const int k = kt * 32 + (lane >> 4) * 8 + j, c = lane & 15;
      wprj[i] = (unsigned short)f2b(proj_w[k * 96 + nt * 16 + c]);
    } else if ((i -= 9216) < 384) { // biases
      float v;
      if (i < 192)      v = qkv_b_a[96 + i];           // k then v biases
      else if (i < 288) v = qkv_b_b[i - 192] * SCALE_Q; // q bias * scale
      else              v = proj_b[i - 288];
      bias[i] = v;
    } else { // gathered rpe, layout [h][row][l15][g], value = old (h,row,col=g*16+l15)
      i -= 384;
      const int h = i >> 12, rest = i & 4095;
      const int row = rest >> 6, l15 = (rest >> 2) & 15, g = i & 3;
      const int col = g * 16 + l15;
      float v;
      if (col >= 49)     v = -1e30f;
      else if (row >= 49) v = 0.f;
      else               v = rpe_table[h * 169 + rpe_index[row * 49 + col]];
      rpe[i] = (unsigned short)f2b(v);
    }
  }
}

// ---------------------------------------------------------------------------
// Fused main kernel: one 7x7 window per 256-thread block (4 waves).
// LDS: 3 regions x 12 KB = 36864 B -> 4 blocks/CU.
//   R0 @0     : xa_hi -> K  -> P(low)  -> out-stage(with R1)
//   R1 @12288 : xb    -> Q  -> P(high) -> out-stage
//   R2 @24576 : xa_lo -> vT -> O
// ---------------------------------------------------------------------------
__global__ __launch_bounds__(256, 4)
void swin_main(const float* __restrict__ xa_in, const float* __restrict__ xb_in,
               const float* __restrict__ nwa, const float* __restrict__ nba,
               const float* __restrict__ nwb, const float* __restrict__ nbb,
               const unsigned char* __restrict__ ws, float* __restrict__ out)
{
  __shared__ unsigned char smem[36864];
  unsigned char* const R0 = smem;
  unsigned char* const R1 = smem + 12288;
  unsigned char* const R2 = smem + 24576;

  const int tid = threadIdx.x;
  const int w   = tid >> 6;   // wave id 0..3
  const int l   = tid & 63;
  const int l15 = l & 15;
  const int lg  = l >> 4;

  const int bw  = blockIdx.x;
  const int bb  = bw >> 10;
  const int hwi = (bw >> 5) & 31;
  const int wwi = bw & 31;
  const int pixbase = (bb * 224 + hwi * 7) * 224 + wwi * 7;

  const f32x4 zf = {0.f, 0.f, 0.f, 0.f};

  // ---------------- Phase A: load + LayerNorm -> bf16 (hi/lo for xa) -------
  {
    const int tok = tid >> 2;
    const int j   = tid & 3;
    const int ch0 = j * 24;
    if (tok < 49) {
      const int gbase = (pixbase + (tok / 7) * 224 + (tok % 7)) * 96 + ch0;
      auto doLN = [&](const float* __restrict__ xin, const float* __restrict__ gw,
                      const float* __restrict__ gb, unsigned char* dstHi,
                      unsigned char* dstLo) {
        float x[24];
        float s = 0.f, s2 = 0.f;
#pragma unroll
        for (int t = 0; t < 6; ++t) {
          const float4 v = *(const float4*)(xin + gbase + t * 4);
          x[t*4+0] = v.x; x[t*4+1] = v.y; x[t*4+2] = v.z; x[t*4+3] = v.w;
          s  += v.x + v.y + v.z + v.w;
          s2 += v.x*v.x + v.y*v.y + v.z*v.z + v.w*v.w;
        }
        s += __shfl_xor(s, 1);  s2 += __shfl_xor(s2, 1);
        s += __shfl_xor(s, 2);  s2 += __shfl_xor(s2, 2);
        const float mu = s * (1.f / 96.f);
        const float rs = rsqrtf(s2 * (1.f / 96.f) - mu * mu + 1e-5f);
        unsigned int hi[12], lo[12];
#pragma unroll
        for (int t = 0; t < 6; ++t) {
          const float4 g  = *(const float4*)(gw + ch0 + t * 4);
          const float4 be = *(const float4*)(gb + ch0 + t * 4);
          const float y0 = (x[t*4+0] - mu) * rs * g.x + be.x;
          const float y1 = (x[t*4+1] - mu) * rs * g.y + be.y;
          const float y2 = (x[t*4+2] - mu) * rs * g.z + be.z;
          const float y3 = (x[t*4+3] - mu) * rs * g.w + be.w;
          const unsigned int h0 = f2bh(y0), h1 = f2bh(y1), h2 = f2bh(y2), h3 = f2bh(y3);
          hi[t*2+0] = h0 | (h1 << 16);
          hi[t*2+1] = h2 | (h3 << 16);
          if (dstLo) {
            const unsigned int l0 = f2bh(y0 - b2f(h0)), l1 = f2bh(y1 - b2f(h1));
            const unsigned int l2 = f2bh(y2 - b2f(h2)), l3 = f2bh(y3 - b2f(h3));
            lo[t*2+0] = l0 | (l1 << 16);
            lo[t*2+1] = l2 | (l3 << 16);
          }
        }
#pragma unroll
        for (int p = 0; p < 3; ++p) {
          const int off = sw192(tok, (ch0 + p * 8) * 2);
          uint4 uh = {hi[p*4+0], hi[p*4+1], hi[p*4+2], hi[p*4+3]};
          *(uint4*)(dstHi + off) = uh;
          if (dstLo) {
            uint4 ul = {lo[p*4+0], lo[p*4+1], lo[p*4+2], lo[p*4+3]};
            *(uint4*)(dstLo + off) = ul;
          }
        }
      };
      doLN(xa_in, nwa, nba, R0, R2);
      doLN(xb_in, nwb, nbb, R1, nullptr);
    } else { // zero pad rows 49..63
      const uint4 z = {0u, 0u, 0u, 0u};
#pragma unroll
      for (int p = 0; p < 3; ++p) {
        const int off = sw192(tok, (ch0 + p * 8) * 2);
        *(uint4*)(R0 + off) = z; *(uint4*)(R1 + off) = z; *(uint4*)(R2 + off) = z;
      }
    }
  }
  __syncthreads(); // barA

  // ---------------- Phase B: QKV GEMMs (n-split across waves) --------------
  // n-tiles 0..5: k (from xa) | 6..11: v hi/lo-split (xa,xa_lo) | 12..17: q (xb)
  {
    f32x4 acc[5][4];
#pragma unroll
    for (int i = 0; i < 5; ++i)
#pragma unroll
      for (int m = 0; m < 4; ++m) acc[i][m] = zf;

    const unsigned char* wqkv = ws + WQKV_OFF;
    const unsigned char* wvlo = ws + WVLO_OFF;

    for (int kt = 0; kt < 3; ++kt) {
      bf16x8 axa[4], axb[4], axlo[4];
      const int abyte = kt * 64 + lg * 16;
#pragma unroll
      for (int mt = 0; mt < 4; ++mt) {
        const int row = mt * 16 + l15;
        const int off = sw192(row, abyte);
        axa[mt]  = *(const bf16x8*)(R0 + off);
        axb[mt]  = *(const bf16x8*)(R1 + off);
        axlo[mt] = *(const bf16x8*)(R2 + off);
      }
#pragma unroll
      for (int i = 0; i < 5; ++i) {
        const int nt = w + 4 * i;
        if (nt < 18) {
          const bf16x8 bw_ = *(const bf16x8*)(wqkv + ((nt * 3 + kt) * 64 + l) * 16);
          if (nt >= 6 && nt < 12) { // v: hi/lo split
            const bf16x8 bl = *(const bf16x8*)(wvlo + (((nt - 6) * 3 + kt) * 64 + l) * 16);
#pragma unroll
            for (int mt = 0; mt < 4; ++mt) {
              acc[i][mt] = __builtin_amdgcn_mfma_f32_16x16x32_bf16(axa[mt],  bw_, acc[i][mt], 0, 0, 0);
              acc[i][mt] = __builtin_amdgcn_mfma_f32_16x16x32_bf16(axlo[mt], bw_, acc[i][mt], 0, 0, 0);
              acc[i][mt] = __builtin_amdgcn_mfma_f32_16x16x32_bf16(axa[mt],  bl,  acc[i][mt], 0, 0, 0);
            }
          } else if (nt >= 12) { // q from xb
#pragma unroll
            for (int mt = 0; mt < 4; ++mt)
              acc[i][mt] = __builtin_amdgcn_mfma_f32_16x16x32_bf16(axb[mt], bw_, acc[i][mt], 0, 0, 0);
          } else { // k from xa
#pragma unroll
            for (int mt = 0; mt < 4; ++mt)
              acc[i][mt] = __builtin_amdgcn_mfma_f32_16x16x32_bf16(axa[mt], bw_, acc[i][mt], 0, 0, 0);
          }
        }
      }
    }

    const float* bias = (const float*)(ws + BIAS_OFF);
#pragma unroll
    for (int i = 0; i < 5; ++i) {
      const int nt = w + 4 * i;
      if (nt < 18) {
        const float bv = bias[nt * 16 + l15];
#pragma unroll
        for (int mt = 0; mt < 4; ++mt) {
          acc[i][mt][0] += bv; acc[i][mt][1] += bv;
          acc[i][mt][2] += bv; acc[i][mt][3] += bv;
        }
      }
    }
    __syncthreads(); // bar1: all Phase-B LDS reads done; xa/xb/xlo now dead
    // K rows -> R0 (over xa). C/D: col=l&15, row=lg*4+r
#pragma unroll
    for (int i = 0; i < 5; ++i) {
      const int nt = w + 4 * i;
      if (nt < 6) {
        const int col = nt * 16 + l15;
#pragma unroll
        for (int mt = 0; mt < 4; ++mt)
#pragma unroll
          for (int r = 0; r < 4; ++r) {
            const int row = mt * 16 + lg * 4 + r;
            *(unsigned short*)(R0 + sw192(row, col * 2)) = f2bh(acc[i][mt][r]);
          }
      }
    }
    // Q rows -> R1 (over xb)
#pragma unroll
    for (int i = 0; i < 5; ++i) {
      const int nt = w + 4 * i;
      if (nt >= 12 && nt < 18) {
        const int col = (nt - 12) * 16 + l15;
#pragma unroll
        for (int mt = 0; mt < 4; ++mt)
#pragma unroll
          for (int r = 0; r < 4; ++r) {
            const int row = mt * 16 + lg * 4 + r;
            *(unsigned short*)(R1 + sw192(row, col * 2)) = f2bh(acc[i][mt][r]);
          }
      }
    }
    // v transposed -> R2 (over xa_lo): vT[dim][key]
#pragma unroll
    for (int i = 0; i < 5; ++i) {
      const int nt = w + 4 * i;
      if (nt >= 6 && nt < 12) {
        const int dim = (nt - 6) * 16 + l15;
#pragma unroll
        for (int mt = 0; mt < 4; ++mt) {
          const int key0 = mt * 16 + lg * 4;
          const unsigned int u0 = (unsigned int)f2bh(acc[i][mt][0]) | ((unsigned int)f2bh(acc[i][mt][1]) << 16);
          const unsigned int u1 = (unsigned int)f2bh(acc[i][mt][2]) | ((unsigned int)f2bh(acc[i][mt][3]) << 16);
          uint2 u = {u0, u1};
          *(uint2*)(R2 + ((dim * 128 + key0 * 2) ^ ((dim & 7) << 4))) = u;
        }
      }
    }
  }
  __syncthreads(); // bar2: K, Q, vT visible

  // ---------------- Phase C: S = q@k^T + rpe, softmax, P -> R0+R1 ----------
  // wave w owns query rows w*16..w*16+15, all 3 heads. P at smem[0..24576).
  {
    // Preload all Q/K fragments to registers, then barrier -> P may overwrite Q/K.
    bf16x8 aq[3], bk[3][4];
    const int qrow = w * 16 + l15;
#pragma unroll
    for (int h = 0; h < 3; ++h) {
      aq[h] = *(const bf16x8*)(R1 + sw192(qrow, h * 64 + lg * 16));
#pragma unroll
      for (int nt = 0; nt < 4; ++nt)
        bk[h][nt] = *(const bf16x8*)(R0 + sw192(nt * 16 + l15, h * 64 + lg * 16));
    }
    __syncthreads(); // bar3: frag reads done; Q/K regions dead

    const unsigned short* rpe = (const unsigned short*)(ws + RPE_OFF);
#pragma unroll
    for (int h = 0; h < 3; ++h) {
      f32x4 s[4];
#pragma unroll
      for (int nt = 0; nt < 4; ++nt)
        s[nt] = __builtin_amdgcn_mfma_f32_16x16x32_bf16(aq[h], bk[h][nt], zf, 0, 0, 0);
#pragma unroll
      for (int r = 0; r < 4; ++r) {
        const int row = w * 16 + lg * 4 + r;
        float sv0 = s[0][r], sv1 = s[1][r], sv2 = s[2][r], sv3 = s[3][r];
        if (row < 49) {
          const uint2 u = *(const uint2*)(rpe + (h * 4096 + row * 64 + l15 * 4));
          sv0 += b2f(u.x & 0xffffu);
          sv1 += b2f(u.x >> 16);
          sv2 += b2f(u.y & 0xffffu);
          sv3 += b2f(u.y >> 16);
        }
        float mx = fmaxf(fmaxf(sv0, sv1), fmaxf(sv2, sv3));
        mx = fmaxf(mx, __shfl_xor(mx, 1));
        mx = fmaxf(mx, __shfl_xor(mx, 2));
        mx = fmaxf(mx, __shfl_xor(mx, 4));
        mx = fmaxf(mx, __shfl_xor(mx, 8));
        const float e0 = __expf(sv0 - mx), e1 = __expf(sv1 - mx);
        const float e2 = __expf(sv2 - mx), e3 = __expf(sv3 - mx);
        float sm = e0 + e1 + e2 + e3;
        sm += __shfl_xor(sm, 1); sm += __shfl_xor(sm, 2);
        sm += __shfl_xor(sm, 4); sm += __shfl_xor(sm, 8);
        const float inv = __fdividef(1.f, sm);
        const int pb = h * 8192 + row * 128;
        const int sz = (row & 7) << 4;
        *(unsigned short*)(smem + ((pb +      l15 * 2) ^ sz)) = f2bh(e0 * inv);
        *(unsigned short*)(smem + ((pb + 32 + l15 * 2) ^ sz)) = f2bh(e1 * inv);
        *(unsigned short*)(smem + ((pb + 64 + l15 * 2) ^ sz)) = f2bh(e2 * inv);
        *(unsigned short*)(smem + ((pb + 96 + l15 * 2) ^ sz)) = f2bh(e3 * inv);
      }
    }
  }
  __syncthreads(); // bar4: P visible

  // ---------------- Phase D: O = P @ V (O stays in registers) --------------
  f32x4 od[3][2];
  {
#pragma unroll
    for (int h = 0; h < 3; ++h) {
      f32x4 o0 = zf, o1 = zf;
#pragma unroll
      for (int kt = 0; kt < 2; ++kt) {
        const int prow = w * 16 + l15;
        const bf16x8 ap = *(const bf16x8*)(smem +
            ((h * 8192 + prow * 128 + kt * 64 + lg * 16) ^ ((prow & 7) << 4)));
        const int d0 = h * 32 + l15;
        const int d1 = d0 + 16;
        const bf16x8 bv0 = *(const bf16x8*)(R2 + ((d0 * 128 + kt * 64 + lg * 16) ^ ((d0 & 7) << 4)));
        const bf16x8 bv1 = *(const bf16x8*)(R2 + ((d1 * 128 + kt * 64 + lg * 16) ^ ((d1 & 7) << 4)));
        o0 = __builtin_amdgcn_mfma_f32_16x16x32_bf16(ap, bv0, o0, 0, 0, 0);
        o1 = __builtin_amdgcn_mfma_f32_16x16x32_bf16(ap, bv1, o1, 0, 0, 0);
      }
      od[h][0] = o0; od[h][1] = o1;
    }
  }
  __syncthreads(); // bar5: all P / vT reads done

  // O -> R2 (over vT, dead)
  {
#pragma unroll
    for (int h = 0; h < 3; ++h)
#pragma unroll
      for (int r = 0; r < 4; ++r) {
        const int row = w * 16 + lg * 4 + r;
        *(unsigned short*)(R2 + sw192(row, (h * 32      + l15) * 2)) = f2bh(od[h][0][r]);
        *(unsigned short*)(R2 + sw192(row, (h * 32 + 16 + l15) * 2)) = f2bh(od[h][1][r]);
      }
  }
  __syncthreads(); // bar6: O visible

  // ---------------- Phase E: proj + stage fp32 result over P (R0+R1) ------
  {
    bf16x8 ao[3];
    const int orow = w * 16 + l15;
#pragma unroll
    for (int kt = 0; kt < 3; ++kt)
      ao[kt] = *(const bf16x8*)(R2 + sw192(orow, kt * 64 + lg * 16));

    f32x4 po[6];
#pragma unroll
    for (int nt = 0; nt < 6; ++nt) po[nt] = zf;
    const unsigned char* wp = ws + WPRJ_OFF;
#pragma unroll
    for (int kt = 0; kt < 3; ++kt) {
#pragma unroll
      for (int nt = 0; nt < 6; ++nt) {
        const bf16x8 bp = *(const bf16x8*)(wp + ((nt * 3 + kt) * 64 + l) * 16);
        po[nt] = __builtin_amdgcn_mfma_f32_16x16x32_bf16(ao[kt], bp, po[nt], 0, 0, 0);
      }
    }
    const float* bias = (const float*)(ws + BIAS_OFF);
#pragma unroll
    for (int nt = 0; nt < 6; ++nt) {
      const float bv = bias[288 + nt * 16 + l15];
#pragma unroll
      for (int r = 0; r < 4; ++r) {
        const int row = w * 16 + lg * 4 + r;
        if (row < 49)
          *(float*)(smem + sw384(row, (nt * 16 + l15) * 4)) = po[nt][r] + bv;
      }
    }
  }
  __syncthreads(); // bar7

  // ---------------- Final: coalesced float4 store (window_reverse) ---------
  {
    for (int i = tid; i < 49 * 24; i += 256) {
      const int tok = i / 24;
      const int cg  = i - tok * 24;
      const float4 v = *(const float4*)(smem + sw384(tok, cg * 16));
      float* dst = out + (long)(pixbase + (tok / 7) * 224 + (tok % 7)) * 96 + cg * 4;
      *(float4*)dst = v;
    }
  }
}

extern "C" void kernel_launch(void* const* d_in, const int* in_sizes, int n_in,
                              void* d_out, int out_size, void* d_ws, size_t ws_size,
                              hipStream_t stream)
{
  const float* rescaled  = (const float*)d_in[0];
  const float* rescaler  = (const float*)d_in[1];
  const float* norm_w_a  = (const float*)d_in[2];
  const float* norm_b_a  = (const float*)d_in[3];
  const float* norm_w_b  = (const float*)d_in[4];
  const float* norm_b_b  = (const float*)d_in[5];
  const float* qkv_w_a   = (const float*)d_in[6];
  const float* qkv_b_a   = (const float*)d_in[7];
  const float* qkv_w_b   = (const float*)d_in[8];
  const float* qkv_b_b   = (const float*)d_in[9];
  const float* rpe_table = (const float*)d_in[10];
  const float* proj_w    = (const float*)d_in[11];
  const float* proj_b    = (const float*)d_in[12];
  const int*   rpe_index = (const int*)d_in[13];
  unsigned char* ws = (unsigned char*)d_ws;
  float* outp = (float*)d_out;

  hipLaunchKernelGGL(prepack_kernel, dim3(64), dim3(256), 0, stream,
                     qkv_w_a, qkv_b_a, qkv_w_b, qkv_b_b, rpe_table, proj_w,
                     proj_b, rpe_index, ws);
  hipLaunchKernelGGL(swin_main, dim3(8192), dim3(256), 0, stream,
                     rescaled, rescaler, norm_w_a, norm_b_a, norm_w_b, norm_b_b,
                     ws, outp);
}

// Round 4
// 271.522 us; speedup vs baseline: 1.7977x; 1.7977x over previous
//
#include <hip/hip_runtime.h>
#include <hip/hip_bf16.h>

#define DI __device__ __forceinline__

typedef __bf16 bf16x8 __attribute__((ext_vector_type(8)));
typedef float f32x4 __attribute__((ext_vector_type(4)));

constexpr float SCALE_Q = 0.17677669529663687f; // 32^-0.5

// workspace byte offsets
constexpr int WQKV_OFF = 0;       // 27648 bf16 = 55296 B  (18 n-tiles x 3 k-iters x 64 lanes x 8)
constexpr int WVLO_OFF = 55296;   //  9216 bf16 = 18432 B  (Wv lo-part fragments)
constexpr int WPRJ_OFF = 73728;   //  9216 bf16 = 18432 B
constexpr int BIAS_OFF = 92160;   //   384 f32  = 1536 B   ([k 0:96][v 96:192][q 192:288][proj 288:384])
constexpr int RPE_OFF  = 93696;   // 12288 bf16 = 24576 B  (rpe2[3][64 row][16 l15][4 g], col=g*16+l15)
// total 118272 B

DI unsigned int f2b(float x) {  // float -> bf16 bits, RNE (software; prepack only)
  union { float f; unsigned int u; } v; v.f = x;
  return (v.u + 0x7fffu + ((v.u >> 16) & 1u)) >> 16;
}
DI unsigned short f2bh(float x) { // float -> bf16 bits via HW cvt (RNE)
  union { __bf16 b; unsigned short u; } v;
  v.b = (__bf16)x;
  return v.u;
}
DI float b2f(unsigned int u) {
  union { unsigned int u; float f; } v; v.u = u << 16;
  return v.f;
}
DI int sw192(int row, int bytecol) { return (row * 192 + bytecol) ^ ((row & 7) << 4); }
DI int sw384(int row, int bytecol) { return (row * 384 + bytecol) ^ ((row & 7) << 4); }

// ---------------------------------------------------------------------------
// Prepack: fragment-ordered bf16 weights (+Wv lo split), biases, gathered RPE.
// B-fragment layout for mfma_f32_16x16x32_bf16: lane l, elem j holds
// B[k = kt*32 + (l>>4)*8 + j][n = nt*16 + (l&15)].
// ---------------------------------------------------------------------------
__global__ void prepack_kernel(const float* __restrict__ qkv_w_a,
                               const float* __restrict__ qkv_b_a,
                               const float* __restrict__ qkv_w_b,
                               const float* __restrict__ qkv_b_b,
                               const float* __restrict__ rpe_table,
                               const float* __restrict__ proj_w,
                               const float* __restrict__ proj_b,
                               const int* __restrict__ rpe_index,
                               unsigned char* __restrict__ ws)
{
  unsigned short* wqkv = (unsigned short*)(ws + WQKV_OFF);
  unsigned short* wvlo = (unsigned short*)(ws + WVLO_OFF);
  unsigned short* wprj = (unsigned short*)(ws + WPRJ_OFF);
  float* bias          = (float*)(ws + BIAS_OFF);
  unsigned short* rpe  = (unsigned short*)(ws + RPE_OFF);

  const int total = 27648 + 9216 + 9216 + 384 + 12288;
  for (int idx = blockIdx.x * blockDim.x + threadIdx.x; idx < total;
       idx += gridDim.x * blockDim.x) {
    int i = idx;
    if (i < 27648) { // [Wk | Wv_hi | Wq*scale] fragments
      const int j = i & 7, lane = (i >> 3) & 63, t = i >> 9;
      const int kt = t % 3, nt = t / 3;
      const int k = kt * 32 + (lane >> 4) * 8 + j, c = lane & 15;
      float v;
      if (nt < 12) v = qkv_w_a[k * 288 + 96 + nt * 16 + c];      // Wk then Wv (cols 96..287)
      else         v = qkv_w_b[k * 288 + (nt - 12) * 16 + c] * SCALE_Q;
      wqkv[i] = (unsigned short)f2b(v);
    } else if ((i -= 27648) < 9216) { // Wv lo-part
      const int j = i & 7, lane = (i >> 3) & 63, t = i >> 9;
      const int kt = t % 3, vnt = t / 3;
      const int k = kt * 32 + (lane >> 4) * 8 + j, c = lane & 15;
      const float full = qkv_w_a[k * 288 + 192 + vnt * 16 + c];
      const unsigned int hi = f2b(full);
      wvlo[i] = (unsigned short)f2b(full - b2f(hi));
    } else if ((i -= 9216) < 9216) { // proj_w
      const int j = i & 7, lane = (i >> 3) & 63, t = i >> 9;
      const int kt = t % 3, nt = t / 3;
      const int k = kt * 32 + (lane >> 4) * 8 + j, c = lane & 15;
      wprj[i] = (unsigned short)f2b(proj_w[k * 96 + nt * 16 + c]);
    } else if ((i -= 9216) < 384) { // biases
      float v;
      if (i < 192)      v = qkv_b_a[96 + i];           // k then v biases
      else if (i < 288) v = qkv_b_b[i - 192] * SCALE_Q; // q bias * scale
      else              v = proj_b[i - 288];
      bias[i] = v;
    } else { // gathered rpe, layout [h][row][l15][g], value = old (h,row,col=g*16+l15)
      i -= 384;
      const int h = i >> 12, rest = i & 4095;
      const int row = rest >> 6, l15 = (rest >> 2) & 15, g = i & 3;
      const int col = g * 16 + l15;
      float v;
      if (col >= 49)     v = -1e30f;
      else if (row >= 49) v = 0.f;
      else               v = rpe_table[h * 169 + rpe_index[row * 49 + col]];
      rpe[i] = (unsigned short)f2b(v);
    }
  }
}

// ---------------------------------------------------------------------------
// Fused main kernel: one 7x7 window per 256-thread block (4 waves).
// LDS: 3 regions x 12 KB = 36864 B.
//   R0 @0     : xa_hi -> K  -> P(low)  -> out-stage(with R1)
//   R1 @12288 : xb    -> Q  -> P(high) -> out-stage
//   R2 @24576 : xa_lo -> vT -> O
// launch_bounds(256,3): total reg budget ~170/wave -> acc stays in AGPRs,
// NO spills (launch_bounds 4 capped at 128 and spilled ~1GB to scratch, R3).
// ---------------------------------------------------------------------------
__global__ __launch_bounds__(256, 3)
void swin_main(const float* __restrict__ xa_in, const float* __restrict__ xb_in,
               const float* __restrict__ nwa, const float* __restrict__ nba,
               const float* __restrict__ nwb, const float* __restrict__ nbb,
               const unsigned char* __restrict__ ws, float* __restrict__ out)
{
  __shared__ unsigned char smem[36864];
  unsigned char* const R0 = smem;
  unsigned char* const R1 = smem + 12288;
  unsigned char* const R2 = smem + 24576;

  const int tid = threadIdx.x;
  const int w   = tid >> 6;   // wave id 0..3
  const int l   = tid & 63;
  const int l15 = l & 15;
  const int lg  = l >> 4;

  const int bw  = blockIdx.x;
  const int bb  = bw >> 10;
  const int hwi = (bw >> 5) & 31;
  const int wwi = bw & 31;
  const int pixbase = (bb * 224 + hwi * 7) * 224 + wwi * 7;

  const f32x4 zf = {0.f, 0.f, 0.f, 0.f};

  // ---------------- Phase A: load + LayerNorm -> bf16 (hi/lo for xa) -------
  {
    const int tok = tid >> 2;
    const int j   = tid & 3;
    const int ch0 = j * 24;
    if (tok < 49) {
      const int gbase = (pixbase + (tok / 7) * 224 + (tok % 7)) * 96 + ch0;
      auto doLN = [&](const float* __restrict__ xin, const float* __restrict__ gw,
                      const float* __restrict__ gb, unsigned char* dstHi,
                      unsigned char* dstLo) {
        float x[24];
        float s = 0.f, s2 = 0.f;
#pragma unroll
        for (int t = 0; t < 6; ++t) {
          const float4 v = *(const float4*)(xin + gbase + t * 4);
          x[t*4+0] = v.x; x[t*4+1] = v.y; x[t*4+2] = v.z; x[t*4+3] = v.w;
          s  += v.x + v.y + v.z + v.w;
          s2 += v.x*v.x + v.y*v.y + v.z*v.z + v.w*v.w;
        }
        s += __shfl_xor(s, 1);  s2 += __shfl_xor(s2, 1);
        s += __shfl_xor(s, 2);  s2 += __shfl_xor(s2, 2);
        const float mu = s * (1.f / 96.f);
        const float rs = rsqrtf(s2 * (1.f / 96.f) - mu * mu + 1e-5f);
        unsigned int hi[12], lo[12];
#pragma unroll
        for (int t = 0; t < 6; ++t) {
          const float4 g  = *(const float4*)(gw + ch0 + t * 4);
          const float4 be = *(const float4*)(gb + ch0 + t * 4);
          const float y0 = (x[t*4+0] - mu) * rs * g.x + be.x;
          const float y1 = (x[t*4+1] - mu) * rs * g.y + be.y;
          const float y2 = (x[t*4+2] - mu) * rs * g.z + be.z;
          const float y3 = (x[t*4+3] - mu) * rs * g.w + be.w;
          const unsigned int h0 = f2bh(y0), h1 = f2bh(y1), h2 = f2bh(y2), h3 = f2bh(y3);
          hi[t*2+0] = h0 | (h1 << 16);
          hi[t*2+1] = h2 | (h3 << 16);
          if (dstLo) {
            const unsigned int l0 = f2bh(y0 - b2f(h0)), l1 = f2bh(y1 - b2f(h1));
            const unsigned int l2 = f2bh(y2 - b2f(h2)), l3 = f2bh(y3 - b2f(h3));
            lo[t*2+0] = l0 | (l1 << 16);
            lo[t*2+1] = l2 | (l3 << 16);
          }
        }
#pragma unroll
        for (int p = 0; p < 3; ++p) {
          const int off = sw192(tok, (ch0 + p * 8) * 2);
          uint4 uh = {hi[p*4+0], hi[p*4+1], hi[p*4+2], hi[p*4+3]};
          *(uint4*)(dstHi + off) = uh;
          if (dstLo) {
            uint4 ul = {lo[p*4+0], lo[p*4+1], lo[p*4+2], lo[p*4+3]};
            *(uint4*)(dstLo + off) = ul;
          }
        }
      };
      doLN(xa_in, nwa, nba, R0, R2);
      doLN(xb_in, nwb, nbb, R1, nullptr);
    } else { // zero pad rows 49..63
      const uint4 z = {0u, 0u, 0u, 0u};
#pragma unroll
      for (int p = 0; p < 3; ++p) {
        const int off = sw192(tok, (ch0 + p * 8) * 2);
        *(uint4*)(R0 + off) = z; *(uint4*)(R1 + off) = z; *(uint4*)(R2 + off) = z;
      }
    }
  }
  __syncthreads(); // barA

  // ---------------- Phase B: QKV GEMMs (n-split across waves) --------------
  // n-tiles 0..5: k (from xa) | 6..11: v hi/lo-split (xa,xa_lo) | 12..17: q (xb)
  {
    f32x4 acc[5][4];
#pragma unroll
    for (int i = 0; i < 5; ++i)
#pragma unroll
      for (int m = 0; m < 4; ++m) acc[i][m] = zf;

    const unsigned char* wqkv = ws + WQKV_OFF;
    const unsigned char* wvlo = ws + WVLO_OFF;

    for (int kt = 0; kt < 3; ++kt) {
      bf16x8 axa[4], axb[4], axlo[4];
      const int abyte = kt * 64 + lg * 16;
#pragma unroll
      for (int mt = 0; mt < 4; ++mt) {
        const int row = mt * 16 + l15;
        const int off = sw192(row, abyte);
        axa[mt]  = *(const bf16x8*)(R0 + off);
        axb[mt]  = *(const bf16x8*)(R1 + off);
        axlo[mt] = *(const bf16x8*)(R2 + off);
      }
#pragma unroll
      for (int i = 0; i < 5; ++i) {
        const int nt = w + 4 * i;
        if (nt < 18) {
          const bf16x8 bw_ = *(const bf16x8*)(wqkv + ((nt * 3 + kt) * 64 + l) * 16);
          if (nt >= 6 && nt < 12) { // v: hi/lo split
            const bf16x8 bl = *(const bf16x8*)(wvlo + (((nt - 6) * 3 + kt) * 64 + l) * 16);
#pragma unroll
            for (int mt = 0; mt < 4; ++mt) {
              acc[i][mt] = __builtin_amdgcn_mfma_f32_16x16x32_bf16(axa[mt],  bw_, acc[i][mt], 0, 0, 0);
              acc[i][mt] = __builtin_amdgcn_mfma_f32_16x16x32_bf16(axlo[mt], bw_, acc[i][mt], 0, 0, 0);
              acc[i][mt] = __builtin_amdgcn_mfma_f32_16x16x32_bf16(axa[mt],  bl,  acc[i][mt], 0, 0, 0);
            }
          } else if (nt >= 12) { // q from xb
#pragma unroll
            for (int mt = 0; mt < 4; ++mt)
              acc[i][mt] = __builtin_amdgcn_mfma_f32_16x16x32_bf16(axb[mt], bw_, acc[i][mt], 0, 0, 0);
          } else { // k from xa
#pragma unroll
            for (int mt = 0; mt < 4; ++mt)
              acc[i][mt] = __builtin_amdgcn_mfma_f32_16x16x32_bf16(axa[mt], bw_, acc[i][mt], 0, 0, 0);
          }
        }
      }
    }

    const float* bias = (const float*)(ws + BIAS_OFF);
#pragma unroll
    for (int i = 0; i < 5; ++i) {
      const int nt = w + 4 * i;
      if (nt < 18) {
        const float bv = bias[nt * 16 + l15];
#pragma unroll
        for (int mt = 0; mt < 4; ++mt) {
          acc[i][mt][0] += bv; acc[i][mt][1] += bv;
          acc[i][mt][2] += bv; acc[i][mt][3] += bv;
        }
      }
    }
    __syncthreads(); // bar1: all Phase-B LDS reads done; xa/xb/xlo now dead
    // K rows -> R0 (over xa). C/D: col=l&15, row=lg*4+r
#pragma unroll
    for (int i = 0; i < 5; ++i) {
      const int nt = w + 4 * i;
      if (nt < 6) {
        const int col = nt * 16 + l15;
#pragma unroll
        for (int mt = 0; mt < 4; ++mt)
#pragma unroll
          for (int r = 0; r < 4; ++r) {
            const int row = mt * 16 + lg * 4 + r;
            *(unsigned short*)(R0 + sw192(row, col * 2)) = f2bh(acc[i][mt][r]);
          }
      }
    }
    // Q rows -> R1 (over xb)
#pragma unroll
    for (int i = 0; i < 5; ++i) {
      const int nt = w + 4 * i;
      if (nt >= 12 && nt < 18) {
        const int col = (nt - 12) * 16 + l15;
#pragma unroll
        for (int mt = 0; mt < 4; ++mt)
#pragma unroll
          for (int r = 0; r < 4; ++r) {
            const int row = mt * 16 + lg * 4 + r;
            *(unsigned short*)(R1 + sw192(row, col * 2)) = f2bh(acc[i][mt][r]);
          }
      }
    }
    // v transposed -> R2 (over xa_lo): vT[dim][key]
#pragma unroll
    for (int i = 0; i < 5; ++i) {
      const int nt = w + 4 * i;
      if (nt >= 6 && nt < 12) {
        const int dim = (nt - 6) * 16 + l15;
#pragma unroll
        for (int mt = 0; mt < 4; ++mt) {
          const int key0 = mt * 16 + lg * 4;
          const unsigned int u0 = (unsigned int)f2bh(acc[i][mt][0]) | ((unsigned int)f2bh(acc[i][mt][1]) << 16);
          const unsigned int u1 = (unsigned int)f2bh(acc[i][mt][2]) | ((unsigned int)f2bh(acc[i][mt][3]) << 16);
          uint2 u = {u0, u1};
          *(uint2*)(R2 + ((dim * 128 + key0 * 2) ^ ((dim & 7) << 4))) = u;
        }
      }
    }
  }
  __syncthreads(); // bar2: K, Q, vT visible

  // ---------------- Phase C: S = q@k^T + rpe, softmax, P -> R0+R1 ----------
  // wave w owns query rows w*16..w*16+15, all 3 heads. P at smem[0..24576).
  {
    // Preload all Q/K fragments to registers, then barrier -> P may overwrite Q/K.
    bf16x8 aq[3], bk[3][4];
    const int qrow = w * 16 + l15;
#pragma unroll
    for (int h = 0; h < 3; ++h) {
      aq[h] = *(const bf16x8*)(R1 + sw192(qrow, h * 64 + lg * 16));
#pragma unroll
      for (int nt = 0; nt < 4; ++nt)
        bk[h][nt] = *(const bf16x8*)(R0 + sw192(nt * 16 + l15, h * 64 + lg * 16));
    }
    __syncthreads(); // bar3: frag reads done; Q/K regions dead

    const unsigned short* rpe = (const unsigned short*)(ws + RPE_OFF);
#pragma unroll
    for (int h = 0; h < 3; ++h) {
      f32x4 s[4];
#pragma unroll
      for (int nt = 0; nt < 4; ++nt)
        s[nt] = __builtin_amdgcn_mfma_f32_16x16x32_bf16(aq[h], bk[h][nt], zf, 0, 0, 0);
#pragma unroll
      for (int r = 0; r < 4; ++r) {
        const int row = w * 16 + lg * 4 + r;
        float sv0 = s[0][r], sv1 = s[1][r], sv2 = s[2][r], sv3 = s[3][r];
        if (row < 49) {
          const uint2 u = *(const uint2*)(rpe + (h * 4096 + row * 64 + l15 * 4));
          sv0 += b2f(u.x & 0xffffu);
          sv1 += b2f(u.x >> 16);
          sv2 += b2f(u.y & 0xffffu);
          sv3 += b2f(u.y >> 16);
        }
        float mx = fmaxf(fmaxf(sv0, sv1), fmaxf(sv2, sv3));
        mx = fmaxf(mx, __shfl_xor(mx, 1));
        mx = fmaxf(mx, __shfl_xor(mx, 2));
        mx = fmaxf(mx, __shfl_xor(mx, 4));
        mx = fmaxf(mx, __shfl_xor(mx, 8));
        const float e0 = __expf(sv0 - mx), e1 = __expf(sv1 - mx);
        const float e2 = __expf(sv2 - mx), e3 = __expf(sv3 - mx);
        float sm = e0 + e1 + e2 + e3;
        sm += __shfl_xor(sm, 1); sm += __shfl_xor(sm, 2);
        sm += __shfl_xor(sm, 4); sm += __shfl_xor(sm, 8);
        const float inv = __fdividef(1.f, sm);
        const int pb = h * 8192 + row * 128;
        const int sz = (row & 7) << 4;
        *(unsigned short*)(smem + ((pb +      l15 * 2) ^ sz)) = f2bh(e0 * inv);
        *(unsigned short*)(smem + ((pb + 32 + l15 * 2) ^ sz)) = f2bh(e1 * inv);
        *(unsigned short*)(smem + ((pb + 64 + l15 * 2) ^ sz)) = f2bh(e2 * inv);
        *(unsigned short*)(smem + ((pb + 96 + l15 * 2) ^ sz)) = f2bh(e3 * inv);
      }
    }
  }
  // NO barrier: P rows are wave-local (written and read only by wave w),
  // and DS ops complete in order within a wave.

  // ---------------- Phase D: O = P @ V (O stays in registers) --------------
  f32x4 od[3][2];
  {
#pragma unroll
    for (int h = 0; h < 3; ++h) {
      f32x4 o0 = zf, o1 = zf;
#pragma unroll
      for (int kt = 0; kt < 2; ++kt) {
        const int prow = w * 16 + l15;
        const bf16x8 ap = *(const bf16x8*)(smem +
            ((h * 8192 + prow * 128 + kt * 64 + lg * 16) ^ ((prow & 7) << 4)));
        const int d0 = h * 32 + l15;
        const int d1 = d0 + 16;
        const bf16x8 bv0 = *(const bf16x8*)(R2 + ((d0 * 128 + kt * 64 + lg * 16) ^ ((d0 & 7) << 4)));
        const bf16x8 bv1 = *(const bf16x8*)(R2 + ((d1 * 128 + kt * 64 + lg * 16) ^ ((d1 & 7) << 4)));
        o0 = __builtin_amdgcn_mfma_f32_16x16x32_bf16(ap, bv0, o0, 0, 0, 0);
        o1 = __builtin_amdgcn_mfma_f32_16x16x32_bf16(ap, bv1, o1, 0, 0, 0);
      }
      od[h][0] = o0; od[h][1] = o1;
    }
  }
  __syncthreads(); // bar5: ALL waves' vT reads done (vT is read cross-wave)

  // O -> R2 (over vT, dead). O rows are wave-local: write+read by wave w only.
  {
#pragma unroll
    for (int h = 0; h < 3; ++h)
#pragma unroll
      for (int r = 0; r < 4; ++r) {
        const int row = w * 16 + lg * 4 + r;
        *(unsigned short*)(R2 + sw192(row, (h * 32      + l15) * 2)) = f2bh(od[h][0][r]);
        *(unsigned short*)(R2 + sw192(row, (h * 32 + 16 + l15) * 2)) = f2bh(od[h][1][r]);
      }
  }
  // NO barrier: O rows are wave-local.

  // ---------------- Phase E: proj + stage fp32 result over P (R0+R1) ------
  {
    bf16x8 ao[3];
    const int orow = w * 16 + l15;
#pragma unroll
    for (int kt = 0; kt < 3; ++kt)
      ao[kt] = *(const bf16x8*)(R2 + sw192(orow, kt * 64 + lg * 16));

    f32x4 po[6];
#pragma unroll
    for (int nt = 0; nt < 6; ++nt) po[nt] = zf;
    const unsigned char* wp = ws + WPRJ_OFF;
#pragma unroll
    for (int kt = 0; kt < 3; ++kt) {
#pragma unroll
      for (int nt = 0; nt < 6; ++nt) {
        const bf16x8 bp = *(const bf16x8*)(wp + ((nt * 3 + kt) * 64 + l) * 16);
        po[nt] = __builtin_amdgcn_mfma_f32_16x16x32_bf16(ao[kt], bp, po[nt], 0, 0, 0);
      }
    }
    const float* bias = (const float*)(ws + BIAS_OFF);
#pragma unroll
    for (int nt = 0; nt < 6; ++nt) {
      const float bv = bias[288 + nt * 16 + l15];
#pragma unroll
      for (int r = 0; r < 4; ++r) {
        const int row = w * 16 + lg * 4 + r;
        if (row < 49)
          *(float*)(smem + sw384(row, (nt * 16 + l15) * 4)) = po[nt][r] + bv;
      }
    }
  }
  __syncthreads(); // bar7: out-stage read cross-wave below

  // ---------------- Final: coalesced float4 store (window_reverse) ---------
  {
    for (int i = tid; i < 49 * 24; i += 256) {
      const int tok = i / 24;
      const int cg  = i - tok * 24;
      const float4 v = *(const float4*)(smem + sw384(tok, cg * 16));
      float* dst = out + (long)(pixbase + (tok / 7) * 224 + (tok % 7)) * 96 + cg * 4;
      *(float4*)dst = v;
    }
  }
}

extern "C" void kernel_launch(void* const* d_in, const int* in_sizes, int n_in,
                              void* d_out, int out_size, void* d_ws, size_t ws_size,
                              hipStream_t stream)
{
  const float* rescaled  = (const float*)d_in[0];
  const float* rescaler  = (const float*)d_in[1];
  const float* norm_w_a  = (const float*)d_in[2];
  const float* norm_b_a  = (const float*)d_in[3];
  const float* norm_w_b  = (const float*)d_in[4];
  const float* norm_b_b  = (const float*)d_in[5];
  const float* qkv_w_a   = (const float*)d_in[6];
  const float* qkv_b_a   = (const float*)d_in[7];
  const float* qkv_w_b   = (const float*)d_in[8];
  const float* qkv_b_b   = (const float*)d_in[9];
  const float* rpe_table = (const float*)d_in[10];
  const float* proj_w    = (const float*)d_in[11];
  const float* proj_b    = (const float*)d_in[12];
  const int*   rpe_index = (const int*)d_in[13];
  unsigned char* ws = (unsigned char*)d_ws;
  float* outp = (float*)d_out;

  hipLaunchKernelGGL(prepack_kernel, dim3(64), dim3(256), 0, stream,
                     qkv_w_a, qkv_b_a, qkv_w_b, qkv_b_b, rpe_table, proj_w,
                     proj_b, rpe_index, ws);
  hipLaunchKernelGGL(swin_main, dim3(8192), dim3(256), 0, stream,
                     rescaled, rescaler, norm_w_a, norm_b_a, norm_w_b, norm_b_b,
                     ws, outp);
}

// Round 5
// 243.722 us; speedup vs baseline: 2.0028x; 1.1141x over previous
//
#include <hip/hip_runtime.h>
#include <hip/hip_bf16.h>

#define DI __device__ __forceinline__

typedef __bf16 bf16x8 __attribute__((ext_vector_type(8)));
typedef float f32x4 __attribute__((ext_vector_type(4)));
typedef unsigned short u16x4 __attribute__((ext_vector_type(4)));

constexpr float SCALE_Q = 0.17677669529663687f; // 32^-0.5

// workspace byte offsets
constexpr int WQKV_OFF = 0;       // 27648 bf16 = 55296 B  (18 n-tiles x 3 k-iters x 64 lanes x 8)
constexpr int WVLO_OFF = 55296;   //  9216 bf16 = 18432 B  (Wv lo-part fragments)
constexpr int WPRJ_OFF = 73728;   //  9216 bf16 = 18432 B
constexpr int BIAS_OFF = 92160;   //   384 f32  = 1536 B   ([k 0:96][v 96:192][q 192:288][proj 288:384])
constexpr int RPE_OFF  = 93696;   // 12288 bf16 = 24576 B  (rpe2[3][64 row][16 l15][4 g], col=g*16+l15)
// total 118272 B

DI unsigned int f2b(float x) {  // float -> bf16 bits, RNE (software; prepack only)
  union { float f; unsigned int u; } v; v.f = x;
  return (v.u + 0x7fffu + ((v.u >> 16) & 1u)) >> 16;
}
DI unsigned short f2bh(float x) { // float -> bf16 bits via HW cvt (RNE)
  union { __bf16 b; unsigned short u; } v;
  v.b = (__bf16)x;
  return v.u;
}
DI float b2f(unsigned int u) {
  union { unsigned int u; float f; } v; v.u = u << 16;
  return v.f;
}
DI int sw192(int row, int bytecol) { return (row * 192 + bytecol) ^ ((row & 7) << 4); }
DI int sw384(int row, int bytecol) { return (row * 384 + bytecol) ^ ((row & 7) << 4); }

// ---------------------------------------------------------------------------
// Prepack: fragment-ordered bf16 weights (+Wv lo split), biases, gathered RPE.
// B-fragment layout for mfma_f32_16x16x32_bf16: lane l, elem j holds
// B[k = kt*32 + (l>>4)*8 + j][n = nt*16 + (l&15)].
// ---------------------------------------------------------------------------
__global__ void prepack_kernel(const float* __restrict__ qkv_w_a,
                               const float* __restrict__ qkv_b_a,
                               const float* __restrict__ qkv_w_b,
                               const float* __restrict__ qkv_b_b,
                               const float* __restrict__ rpe_table,
                               const float* __restrict__ proj_w,
                               const float* __restrict__ proj_b,
                               const int* __restrict__ rpe_index,
                               unsigned char* __restrict__ ws)
{
  unsigned short* wqkv = (unsigned short*)(ws + WQKV_OFF);
  unsigned short* wvlo = (unsigned short*)(ws + WVLO_OFF);
  unsigned short* wprj = (unsigned short*)(ws + WPRJ_OFF);
  float* bias          = (float*)(ws + BIAS_OFF);
  unsigned short* rpe  = (unsigned short*)(ws + RPE_OFF);

  const int total = 27648 + 9216 + 9216 + 384 + 12288;
  for (int idx = blockIdx.x * blockDim.x + threadIdx.x; idx < total;
       idx += gridDim.x * blockDim.x) {
    int i = idx;
    if (i < 27648) { // [Wk | Wv_hi | Wq*scale] fragments
      const int j = i & 7, lane = (i >> 3) & 63, t = i >> 9;
      const int kt = t % 3, nt = t / 3;
      const int k = kt * 32 + (lane >> 4) * 8 + j, c = lane & 15;
      float v;
      if (nt < 12) v = qkv_w_a[k * 288 + 96 + nt * 16 + c];      // Wk then Wv (cols 96..287)
      else         v = qkv_w_b[k * 288 + (nt - 12) * 16 + c] * SCALE_Q;
      wqkv[i] = (unsigned short)f2b(v);
    } else if ((i -= 27648) < 9216) { // Wv lo-part
      const int j = i & 7, lane = (i >> 3) & 63, t = i >> 9;
      const int kt = t % 3, vnt = t / 3;
      const int k = kt * 32 + (lane >> 4) * 8 + j, c = lane & 15;
      const float full = qkv_w_a[k * 288 + 192 + vnt * 16 + c];
      const unsigned int hi = f2b(full);
      wvlo[i] = (unsigned short)f2b(full - b2f(hi));
    } else if ((i -= 9216) < 9216) { // proj_w
      const int j = i & 7, lane = (i >> 3) & 63, t = i >> 9;
      const int kt = t % 3, nt = t / 3;
      const int k = kt * 32 + (lane >> 4) * 8 + j, c = lane & 15;
      wprj[i] = (unsigned short)f2b(proj_w[k * 96 + nt * 16 + c]);
    } else if ((i -= 9216) < 384) { // biases
      float v;
      if (i < 192)      v = qkv_b_a[96 + i];           // k then v biases
      else if (i < 288) v = qkv_b_b[i - 192] * SCALE_Q; // q bias * scale
      else              v = proj_b[i - 288];
      bias[i] = v;
    } else { // gathered rpe, layout [h][row][l15][g], value = old (h,row,col=g*16+l15)
      i -= 384;
      const int h = i >> 12, rest = i & 4095;
      const int row = rest >> 6, l15 = (rest >> 2) & 15, g = i & 3;
      const int col = g * 16 + l15;
      float v;
      if (col >= 49)     v = -1e30f;
      else if (row >= 49) v = 0.f;
      else               v = rpe_table[h * 169 + rpe_index[row * 49 + col]];
      rpe[i] = (unsigned short)f2b(v);
    }
  }
}

// ---------------------------------------------------------------------------
// Fused main kernel: one 7x7 window per 256-thread block (4 waves).
// LDS: 3 regions x 12 KB + 8 KB P-buffer = 45056 B (3 blocks/CU).
//   R0 @0     : xa_hi -> K            -> out-stage(with R1)
//   R1 @12288 : xb    -> Q            -> out-stage
//   R2 @24576 : xa_lo -> vT           -> O
//   PH @36864 : per-head P (pi-permuted keys)
// Key permutation pi(key) = (key&15)*4 + (key>>4) applied to BOTH P and vT
// (the PV MFMA contracts in pi-order; any consistent bijection is valid).
// ---------------------------------------------------------------------------
__global__ __launch_bounds__(256, 3)
void swin_main(const float* __restrict__ xa_in, const float* __restrict__ xb_in,
               const float* __restrict__ nwa, const float* __restrict__ nba,
               const float* __restrict__ nwb, const float* __restrict__ nbb,
               const unsigned char* __restrict__ ws, float* __restrict__ out)
{
  __shared__ unsigned char smem[45056];
  unsigned char* const R0 = smem;
  unsigned char* const R1 = smem + 12288;
  unsigned char* const R2 = smem + 24576;
  unsigned char* const PH = smem + 36864;

  const int tid = threadIdx.x;
  const int w   = tid >> 6;   // wave id 0..3
  const int l   = tid & 63;
  const int l15 = l & 15;
  const int lg  = l >> 4;

  const int bw  = blockIdx.x;
  const int bb  = bw >> 10;
  const int hwi = (bw >> 5) & 31;
  const int wwi = bw & 31;
  const int pixbase = (bb * 224 + hwi * 7) * 224 + wwi * 7;

  const f32x4 zf = {0.f, 0.f, 0.f, 0.f};

  // ---------------- Phase A: load + LayerNorm -> bf16 (hi/lo for xa) -------
  {
    const int tok = tid >> 2;
    const int j   = tid & 3;
    const int ch0 = j * 24;
    if (tok < 49) {
      const int gbase = (pixbase + (tok / 7) * 224 + (tok % 7)) * 96 + ch0;
      auto doLN = [&](const float* __restrict__ xin, const float* __restrict__ gw,
                      const float* __restrict__ gb, unsigned char* dstHi,
                      unsigned char* dstLo) {
        float x[24];
        float s = 0.f, s2 = 0.f;
#pragma unroll
        for (int t = 0; t < 6; ++t) {
          const float4 v = *(const float4*)(xin + gbase + t * 4);
          x[t*4+0] = v.x; x[t*4+1] = v.y; x[t*4+2] = v.z; x[t*4+3] = v.w;
          s  += v.x + v.y + v.z + v.w;
          s2 += v.x*v.x + v.y*v.y + v.z*v.z + v.w*v.w;
        }
        s += __shfl_xor(s, 1);  s2 += __shfl_xor(s2, 1);
        s += __shfl_xor(s, 2);  s2 += __shfl_xor(s2, 2);
        const float mu = s * (1.f / 96.f);
        const float rs = rsqrtf(s2 * (1.f / 96.f) - mu * mu + 1e-5f);
        unsigned int hi[12], lo[12];
#pragma unroll
        for (int t = 0; t < 6; ++t) {
          const float4 g  = *(const float4*)(gw + ch0 + t * 4);
          const float4 be = *(const float4*)(gb + ch0 + t * 4);
          const float y0 = (x[t*4+0] - mu) * rs * g.x + be.x;
          const float y1 = (x[t*4+1] - mu) * rs * g.y + be.y;
          const float y2 = (x[t*4+2] - mu) * rs * g.z + be.z;
          const float y3 = (x[t*4+3] - mu) * rs * g.w + be.w;
          const unsigned int h0 = f2bh(y0), h1 = f2bh(y1), h2 = f2bh(y2), h3 = f2bh(y3);
          hi[t*2+0] = h0 | (h1 << 16);
          hi[t*2+1] = h2 | (h3 << 16);
          if (dstLo) {
            const unsigned int l0 = f2bh(y0 - b2f(h0)), l1 = f2bh(y1 - b2f(h1));
            const unsigned int l2 = f2bh(y2 - b2f(h2)), l3 = f2bh(y3 - b2f(h3));
            lo[t*2+0] = l0 | (l1 << 16);
            lo[t*2+1] = l2 | (l3 << 16);
          }
        }
#pragma unroll
        for (int p = 0; p < 3; ++p) {
          const int off = sw192(tok, (ch0 + p * 8) * 2);
          uint4 uh = {hi[p*4+0], hi[p*4+1], hi[p*4+2], hi[p*4+3]};
          *(uint4*)(dstHi + off) = uh;
          if (dstLo) {
            uint4 ul = {lo[p*4+0], lo[p*4+1], lo[p*4+2], lo[p*4+3]};
            *(uint4*)(dstLo + off) = ul;
          }
        }
      };
      doLN(xa_in, nwa, nba, R0, R2);
      doLN(xb_in, nwb, nbb, R1, nullptr);
    } else { // zero pad rows 49..63
      const uint4 z = {0u, 0u, 0u, 0u};
#pragma unroll
      for (int p = 0; p < 3; ++p) {
        const int off = sw192(tok, (ch0 + p * 8) * 2);
        *(uint4*)(R0 + off) = z; *(uint4*)(R1 + off) = z; *(uint4*)(R2 + off) = z;
      }
    }
  }
  __syncthreads(); // barA

  // ---------------- Phase B: QKV GEMMs (n-split across waves) --------------
  // n-tiles 0..5: k (from xa) | 6..11: v hi/lo-split (xa,xa_lo) | 12..17: q (xb)
  {
    const float* bias = (const float*)(ws + BIAS_OFF);
    f32x4 acc[5][4];
#pragma unroll
    for (int i = 0; i < 5; ++i) {
      const int nt = w + 4 * i;
      const float bv = (nt < 18) ? bias[nt * 16 + l15] : 0.f;
      const f32x4 bvv = {bv, bv, bv, bv};
#pragma unroll
      for (int m = 0; m < 4; ++m) acc[i][m] = bvv; // bias as acc-init
    }

    const unsigned char* wqkv = ws + WQKV_OFF;
    const unsigned char* wvlo = ws + WVLO_OFF;

    for (int kt = 0; kt < 3; ++kt) {
      bf16x8 axa[4], axb[4], axlo[4];
      const int abyte = kt * 64 + lg * 16;
#pragma unroll
      for (int mt = 0; mt < 4; ++mt) {
        const int row = mt * 16 + l15;
        const int off = sw192(row, abyte);
        axa[mt]  = *(const bf16x8*)(R0 + off);
        axb[mt]  = *(const bf16x8*)(R1 + off);
        axlo[mt] = *(const bf16x8*)(R2 + off);
      }
#pragma unroll
      for (int i = 0; i < 5; ++i) {
        const int nt = w + 4 * i;
        if (nt < 18) {
          const bf16x8 bw_ = *(const bf16x8*)(wqkv + ((nt * 3 + kt) * 64 + l) * 16);
          if (nt >= 6 && nt < 12) { // v: hi/lo split
            const bf16x8 bl = *(const bf16x8*)(wvlo + (((nt - 6) * 3 + kt) * 64 + l) * 16);
#pragma unroll
            for (int mt = 0; mt < 4; ++mt) {
              acc[i][mt] = __builtin_amdgcn_mfma_f32_16x16x32_bf16(axa[mt],  bw_, acc[i][mt], 0, 0, 0);
              acc[i][mt] = __builtin_amdgcn_mfma_f32_16x16x32_bf16(axlo[mt], bw_, acc[i][mt], 0, 0, 0);
              acc[i][mt] = __builtin_amdgcn_mfma_f32_16x16x32_bf16(axa[mt],  bl,  acc[i][mt], 0, 0, 0);
            }
          } else if (nt >= 12) { // q from xb
#pragma unroll
            for (int mt = 0; mt < 4; ++mt)
              acc[i][mt] = __builtin_amdgcn_mfma_f32_16x16x32_bf16(axb[mt], bw_, acc[i][mt], 0, 0, 0);
          } else { // k from xa
#pragma unroll
            for (int mt = 0; mt < 4; ++mt)
              acc[i][mt] = __builtin_amdgcn_mfma_f32_16x16x32_bf16(axa[mt], bw_, acc[i][mt], 0, 0, 0);
          }
        }
      }
    }
    __syncthreads(); // bar1: all Phase-B LDS reads done; xa/xb/xlo now dead

    // K rows -> R0 (over xa). C/D: col=l&15, row=lg*4+r
#pragma unroll
    for (int i = 0; i < 5; ++i) {
      const int nt = w + 4 * i;
      if (nt < 6) {
        const int col = nt * 16 + l15;
#pragma unroll
        for (int mt = 0; mt < 4; ++mt)
#pragma unroll
          for (int r = 0; r < 4; ++r) {
            const int row = mt * 16 + lg * 4 + r;
            *(unsigned short*)(R0 + sw192(row, col * 2)) = f2bh(acc[i][mt][r]);
          }
      }
    }
    // Q rows -> R1 (over xb)
#pragma unroll
    for (int i = 0; i < 5; ++i) {
      const int nt = w + 4 * i;
      if (nt >= 12 && nt < 18) {
        const int col = (nt - 12) * 16 + l15;
#pragma unroll
        for (int mt = 0; mt < 4; ++mt)
#pragma unroll
          for (int r = 0; r < 4; ++r) {
            const int row = mt * 16 + lg * 4 + r;
            *(unsigned short*)(R1 + sw192(row, col * 2)) = f2bh(acc[i][mt][r]);
          }
      }
    }
    // v -> R2 (over xa_lo), pi-permuted keys: byte 2*pi(key) within row dim.
    // key = mt*16 + lg*4 + r  ->  pi = (lg*4+r)*4 + mt  ->  byte lg*32+r*8+mt*2
#pragma unroll
    for (int i = 0; i < 5; ++i) {
      const int nt = w + 4 * i;
      if (nt >= 6 && nt < 12) {
        const int dim = (nt - 6) * 16 + l15;
#pragma unroll
        for (int r = 0; r < 4; ++r) {
          u16x4 u = {f2bh(acc[i][0][r]), f2bh(acc[i][1][r]),
                     f2bh(acc[i][2][r]), f2bh(acc[i][3][r])};
          *(u16x4*)(R2 + ((dim * 128 + lg * 32 + r * 8) ^ ((dim & 7) << 4))) = u;
        }
      }
    }
  }
  __syncthreads(); // bar2: K, Q, vT visible

  // ---------------- Phase C+D fused: per head QK^T+rpe+softmax+PV ----------
  // wave w owns query rows w*16..w*16+15; P_h is wave-local in PH.
  f32x4 od[3][2];
  {
    const unsigned short* rpe = (const unsigned short*)(ws + RPE_OFF);
    const int qrow = w * 16 + l15;

    // prefetch all 12 RPE uint2 (L2) up front: latency hides under head 0 MFMAs
    uint2 rp[3][4];
#pragma unroll
    for (int h = 0; h < 3; ++h)
#pragma unroll
      for (int r = 0; r < 4; ++r) {
        const int row = w * 16 + lg * 4 + r;
        rp[h][r] = *(const uint2*)(rpe + (h * 4096 + row * 64 + l15 * 4));
      }

#pragma unroll
    for (int h = 0; h < 3; ++h) {
      const bf16x8 aq = *(const bf16x8*)(R1 + sw192(qrow, h * 64 + lg * 16));
      f32x4 s[4];
#pragma unroll
      for (int nt = 0; nt < 4; ++nt) {
        const bf16x8 bk = *(const bf16x8*)(R0 + sw192(nt * 16 + l15, h * 64 + lg * 16));
        s[nt] = __builtin_amdgcn_mfma_f32_16x16x32_bf16(aq, bk, zf, 0, 0, 0);
      }
#pragma unroll
      for (int r = 0; r < 4; ++r) {
        const int row = w * 16 + lg * 4 + r;
        const uint2 u = rp[h][r];
        const float sv0 = s[0][r] + b2f(u.x & 0xffffu);
        const float sv1 = s[1][r] + b2f(u.x >> 16);
        const float sv2 = s[2][r] + b2f(u.y & 0xffffu);
        const float sv3 = s[3][r] + b2f(u.y >> 16);
        float mx = fmaxf(fmaxf(sv0, sv1), fmaxf(sv2, sv3));
        mx = fmaxf(mx, __shfl_xor(mx, 1));
        mx = fmaxf(mx, __shfl_xor(mx, 2));
        mx = fmaxf(mx, __shfl_xor(mx, 4));
        mx = fmaxf(mx, __shfl_xor(mx, 8));
        const float e0 = __expf(sv0 - mx), e1 = __expf(sv1 - mx);
        const float e2 = __expf(sv2 - mx), e3 = __expf(sv3 - mx);
        float sm = e0 + e1 + e2 + e3;
        sm += __shfl_xor(sm, 1); sm += __shfl_xor(sm, 2);
        sm += __shfl_xor(sm, 4); sm += __shfl_xor(sm, 8);
        const float inv = __fdividef(1.f, sm);
        // pi-permuted P store: keys {l15,l15+16,l15+32,l15+48} -> bytes l15*8+{0,2,4,6}
        u16x4 pq = {f2bh(e0 * inv), f2bh(e1 * inv), f2bh(e2 * inv), f2bh(e3 * inv)};
        *(u16x4*)(PH + ((row * 128 + l15 * 8) ^ ((row & 7) << 4))) = pq;
      }
      // PV for this head (reads P_h in pi order, vT in pi order)
      f32x4 o0 = zf, o1 = zf;
#pragma unroll
      for (int kt = 0; kt < 2; ++kt) {
        const bf16x8 ap = *(const bf16x8*)(PH +
            ((qrow * 128 + kt * 64 + lg * 16) ^ ((qrow & 7) << 4)));
        const int d0 = h * 32 + l15;
        const int d1 = d0 + 16;
        const bf16x8 bv0 = *(const bf16x8*)(R2 + ((d0 * 128 + kt * 64 + lg * 16) ^ ((d0 & 7) << 4)));
        const bf16x8 bv1 = *(const bf16x8*)(R2 + ((d1 * 128 + kt * 64 + lg * 16) ^ ((d1 & 7) << 4)));
        o0 = __builtin_amdgcn_mfma_f32_16x16x32_bf16(ap, bv0, o0, 0, 0, 0);
        o1 = __builtin_amdgcn_mfma_f32_16x16x32_bf16(ap, bv1, o1, 0, 0, 0);
      }
      od[h][0] = o0; od[h][1] = o1;
    }
  }
  __syncthreads(); // bar5: all waves' K/Q/vT reads done

  // O -> R2 (over vT, dead). O rows are wave-local: write+read by wave w only.
  {
#pragma unroll
    for (int h = 0; h < 3; ++h)
#pragma unroll
      for (int r = 0; r < 4; ++r) {
        const int row = w * 16 + lg * 4 + r;
        *(unsigned short*)(R2 + sw192(row, (h * 32      + l15) * 2)) = f2bh(od[h][0][r]);
        *(unsigned short*)(R2 + sw192(row, (h * 32 + 16 + l15) * 2)) = f2bh(od[h][1][r]);
      }
  }
  // NO barrier: O rows are wave-local.

  // ---------------- Phase E: proj + stage fp32 result over K/Q (R0+R1) ----
  {
    bf16x8 ao[3];
    const int orow = w * 16 + l15;
#pragma unroll
    for (int kt = 0; kt < 3; ++kt)
      ao[kt] = *(const bf16x8*)(R2 + sw192(orow, kt * 64 + lg * 16));

    const float* bias = (const float*)(ws + BIAS_OFF);
    f32x4 po[6];
#pragma unroll
    for (int nt = 0; nt < 6; ++nt) {
      const float bv = bias[288 + nt * 16 + l15];
      po[nt] = {bv, bv, bv, bv}; // proj bias as acc-init
    }
    const unsigned char* wp = ws + WPRJ_OFF;
#pragma unroll
    for (int kt = 0; kt < 3; ++kt) {
#pragma unroll
      for (int nt = 0; nt < 6; ++nt) {
        const bf16x8 bp = *(const bf16x8*)(wp + ((nt * 3 + kt) * 64 + l) * 16);
        po[nt] = __builtin_amdgcn_mfma_f32_16x16x32_bf16(ao[kt], bp, po[nt], 0, 0, 0);
      }
    }
#pragma unroll
    for (int nt = 0; nt < 6; ++nt) {
#pragma unroll
      for (int r = 0; r < 4; ++r) {
        const int row = w * 16 + lg * 4 + r;
        if (row < 49)
          *(float*)(smem + sw384(row, (nt * 16 + l15) * 4)) = po[nt][r];
      }
    }
  }
  __syncthreads(); // bar7: out-stage read cross-wave below

  // ---------------- Final: coalesced float4 store (window_reverse) ---------
  {
    for (int i = tid; i < 49 * 24; i += 256) {
      const int tok = i / 24;
      const int cg  = i - tok * 24;
      const float4 v = *(const float4*)(smem + sw384(tok, cg * 16));
      float* dst = out + (long)(pixbase + (tok / 7) * 224 + (tok % 7)) * 96 + cg * 4;
      *(float4*)dst = v;
    }
  }
}

extern "C" void kernel_launch(void* const* d_in, const int* in_sizes, int n_in,
                              void* d_out, int out_size, void* d_ws, size_t ws_size,
                              hipStream_t stream)
{
  const float* rescaled  = (const float*)d_in[0];
  const float* rescaler  = (const float*)d_in[1];
  const float* norm_w_a  = (const float*)d_in[2];
  const float* norm_b_a  = (const float*)d_in[3];
  const float* norm_w_b  = (const float*)d_in[4];
  const float* norm_b_b  = (const float*)d_in[5];
  const float* qkv_w_a   = (const float*)d_in[6];
  const float* qkv_b_a   = (const float*)d_in[7];
  const float* qkv_w_b   = (const float*)d_in[8];
  const float* qkv_b_b   = (const float*)d_in[9];
  const float* rpe_table = (const float*)d_in[10];
  const float* proj_w    = (const float*)d_in[11];
  const float* proj_b    = (const float*)d_in[12];
  const int*   rpe_index = (const int*)d_in[13];
  unsigned char* ws = (unsigned char*)d_ws;
  float* outp = (float*)d_out;

  hipLaunchKernelGGL(prepack_kernel, dim3(64), dim3(256), 0, stream,
                     qkv_w_a, qkv_b_a, qkv_w_b, qkv_b_b, rpe_table, proj_w,
                     proj_b, rpe_index, ws);
  hipLaunchKernelGGL(swin_main, dim3(8192), dim3(256), 0, stream,
                     rescaled, rescaler, norm_w_a, norm_b_a, norm_w_b, norm_b_b,
                     ws, outp);
}

// Round 7
// 233.005 us; speedup vs baseline: 2.0949x; 1.0460x over previous
//
#include <hip/hip_runtime.h>
#include <hip/hip_bf16.h>

#define DI __device__ __forceinline__

typedef __bf16 bf16x8 __attribute__((ext_vector_type(8)));
typedef float f32x4 __attribute__((ext_vector_type(4)));

constexpr float SCALE_Q = 0.17677669529663687f; // 32^-0.5

// workspace byte offsets
constexpr int WQKV_OFF = 0;       // 27648 bf16 = 55296 B  (18 n-tiles x 3 k-iters x 64 lanes x 8)
constexpr int WVLO_OFF = 55296;   //  9216 bf16 = 18432 B  (Wv lo-part fragments)
constexpr int WPRJ_OFF = 73728;   //  9216 bf16 = 18432 B
constexpr int BIAS_OFF = 92160;   //   384 f32  = 1536 B   ([k 0:96][v 96:192][q 192:288][proj 288:384])
constexpr int RPE_OFF  = 93696;   // 12288 bf16 = 24576 B  (rpe3[h][qrow 64][lg 4][mt 4][r 4], key=mt*16+lg*4+r)
// total 118272 B

DI unsigned int f2b(float x) {  // float -> bf16 bits, RNE (software; prepack only)
  union { float f; unsigned int u; } v; v.f = x;
  return (v.u + 0x7fffu + ((v.u >> 16) & 1u)) >> 16;
}
DI unsigned int f2bh(float x) { // float -> bf16 bits via HW cvt (RNE)
  union { __bf16 b; unsigned short u; } v;
  v.b = (__bf16)x;
  return (unsigned int)v.u;
}
DI float b2f(unsigned int u) {
  union { unsigned int u; float f; } v; v.u = u << 16;
  return v.f;
}
DI int sw192(int row, int bytecol) { return (row * 192 + bytecol) ^ ((row & 7) << 4); }
DI int sw384(int row, int bytecol) { return (row * 384 + bytecol) ^ ((row & 7) << 4); }

// ---------------------------------------------------------------------------
// Prepack: fragment-ordered bf16 weights (+Wv lo split), biases, gathered RPE.
// B-fragment layout for mfma_f32_16x16x32_bf16: lane l, elem j holds
// B[k = kt*32 + (l>>4)*8 + j][n = nt*16 + (l&15)].
// ---------------------------------------------------------------------------
__global__ void prepack_kernel(const float* __restrict__ qkv_w_a,
                               const float* __restrict__ qkv_b_a,
                               const float* __restrict__ qkv_w_b,
                               const float* __restrict__ qkv_b_b,
                               const float* __restrict__ rpe_table,
                               const float* __restrict__ proj_w,
                               const float* __restrict__ proj_b,
                               const int* __restrict__ rpe_index,
                               unsigned char* __restrict__ ws)
{
  unsigned short* wqkv = (unsigned short*)(ws + WQKV_OFF);
  unsigned short* wvlo = (unsigned short*)(ws + WVLO_OFF);
  unsigned short* wprj = (unsigned short*)(ws + WPRJ_OFF);
  float* bias          = (float*)(ws + BIAS_OFF);
  unsigned short* rpe  = (unsigned short*)(ws + RPE_OFF);

  const int total = 27648 + 9216 + 9216 + 384 + 12288;
  for (int idx = blockIdx.x * blockDim.x + threadIdx.x; idx < total;
       idx += gridDim.x * blockDim.x) {
    int i = idx;
    if (i < 27648) { // [Wk | Wv_hi | Wq*scale] fragments
      const int j = i & 7, lane = (i >> 3) & 63, t = i >> 9;
      const int kt = t % 3, nt = t / 3;
      const int k = kt * 32 + (lane >> 4) * 8 + j, c = lane & 15;
      float v;
      if (nt < 12) v = qkv_w_a[k * 288 + 96 + nt * 16 + c];      // Wk then Wv (cols 96..287)
      else         v = qkv_w_b[k * 288 + (nt - 12) * 16 + c] * SCALE_Q;
      wqkv[i] = (unsigned short)f2b(v);
    } else if ((i -= 27648) < 9216) { // Wv lo-part
      const int j = i & 7, lane = (i >> 3) & 63, t = i >> 9;
      const int kt = t % 3, vnt = t / 3;
      const int k = kt * 32 + (lane >> 4) * 8 + j, c = lane & 15;
      const float full = qkv_w_a[k * 288 + 192 + vnt * 16 + c];
      const unsigned int hi = f2b(full);
      wvlo[i] = (unsigned short)f2b(full - b2f(hi));
    } else if ((i -= 9216) < 9216) { // proj_w
      const int j = i & 7, lane = (i >> 3) & 63, t = i >> 9;
      const int kt = t % 3, nt = t / 3;
      const int k = kt * 32 + (lane >> 4) * 8 + j, c = lane & 15;
      wprj[i] = (unsigned short)f2b(proj_w[k * 96 + nt * 16 + c]);
    } else if ((i -= 9216) < 384) { // biases
      float v;
      if (i < 192)      v = qkv_b_a[96 + i];           // k then v biases
      else if (i < 288) v = qkv_b_b[i - 192] * SCALE_Q; // q bias * scale
      else              v = proj_b[i - 288];
      bias[i] = v;
    } else { // rpe3 [h][qrow][lg][mt][r]: value = rpe(h, qrow, key=mt*16+lg*4+r)
      i -= 384;
      const int h = i >> 12, rest = i & 4095;
      const int qrow = rest >> 6, lg = (rest >> 4) & 3, mt = (rest >> 2) & 3, r = i & 3;
      const int key = mt * 16 + lg * 4 + r;
      float v;
      if (key >= 49)       v = -1e30f;
      else if (qrow >= 49) v = 0.f;
      else                 v = rpe_table[h * 169 + rpe_index[qrow * 49 + key]];
      rpe[i] = (unsigned short)f2b(v);
    }
  }
}

// ---------------------------------------------------------------------------
// Fused main kernel: one 7x7 window per 256-thread block (4 waves).
// LDS: 3 regions x 12 KB + PB 8 KB + OB 8 KB = 53248 B (3 blocks/CU).
//   R0 @0     : xa_hi -> K   -> out-stage(with R1)
//   R1 @12288 : xb    -> Q   -> out-stage
//   R2 @24576 : xa_lo -> vT  (natural key order)
//   PB @36864 : wave-local P^T staging [64 qrow][64 key] bf16, swz (qrow&7)<<4
//   OB @45056 : wave-local O staging   [64 qrow][64 B]     , swz (qrow&7)<<4
// Swapped-operand S^T = K x Q^T: each lane owns one q-row; softmax in-lane +
// 2 shfls; P/O fragment relayouts go through wave-local LDS (no barriers;
// same-wave DS ops are ordered). NOTE: ds_bpermute gathers were WRONG here
// (src-lane register selection), hence the LDS round-trip.
// ---------------------------------------------------------------------------
__global__ __launch_bounds__(256, 3)
void swin_main(const float* __restrict__ xa_in, const float* __restrict__ xb_in,
               const float* __restrict__ nwa, const float* __restrict__ nba,
               const float* __restrict__ nwb, const float* __restrict__ nbb,
               const unsigned char* __restrict__ ws, float* __restrict__ out)
{
  __shared__ unsigned char smem[53248];
  unsigned char* const R0 = smem;
  unsigned char* const R1 = smem + 12288;
  unsigned char* const R2 = smem + 24576;
  unsigned char* const PB = smem + 36864;
  unsigned char* const OB = smem + 45056;

  const int tid = threadIdx.x;
  const int w   = tid >> 6;   // wave id 0..3
  const int l   = tid & 63;
  const int l15 = l & 15;
  const int lg  = l >> 4;

  const int bw  = blockIdx.x;
  const int bb  = bw >> 10;
  const int hwi = (bw >> 5) & 31;
  const int wwi = bw & 31;
  const int pixbase = (bb * 224 + hwi * 7) * 224 + wwi * 7;

  const f32x4 zf = {0.f, 0.f, 0.f, 0.f};

  // ---------------- Phase A: load + LayerNorm -> bf16 (hi/lo for xa) -------
  {
    const int tok = tid >> 2;
    const int j   = tid & 3;
    const int ch0 = j * 24;
    if (tok < 49) {
      const int gbase = (pixbase + (tok / 7) * 224 + (tok % 7)) * 96 + ch0;
      auto doLN = [&](const float* __restrict__ xin, const float* __restrict__ gw,
                      const float* __restrict__ gb, unsigned char* dstHi,
                      unsigned char* dstLo) {
        float x[24];
        float s = 0.f, s2 = 0.f;
#pragma unroll
        for (int t = 0; t < 6; ++t) {
          const float4 v = *(const float4*)(xin + gbase + t * 4);
          x[t*4+0] = v.x; x[t*4+1] = v.y; x[t*4+2] = v.z; x[t*4+3] = v.w;
          s  += v.x + v.y + v.z + v.w;
          s2 += v.x*v.x + v.y*v.y + v.z*v.z + v.w*v.w;
        }
        s += __shfl_xor(s, 1);  s2 += __shfl_xor(s2, 1);
        s += __shfl_xor(s, 2);  s2 += __shfl_xor(s2, 2);
        const float mu = s * (1.f / 96.f);
        const float rs = rsqrtf(s2 * (1.f / 96.f) - mu * mu + 1e-5f);
        unsigned int hi[12], lo[12];
#pragma unroll
        for (int t = 0; t < 6; ++t) {
          const float4 g  = *(const float4*)(gw + ch0 + t * 4);
          const float4 be = *(const float4*)(gb + ch0 + t * 4);
          const float y0 = (x[t*4+0] - mu) * rs * g.x + be.x;
          const float y1 = (x[t*4+1] - mu) * rs * g.y + be.y;
          const float y2 = (x[t*4+2] - mu) * rs * g.z + be.z;
          const float y3 = (x[t*4+3] - mu) * rs * g.w + be.w;
          const unsigned int h0 = f2bh(y0), h1 = f2bh(y1), h2 = f2bh(y2), h3 = f2bh(y3);
          hi[t*2+0] = h0 | (h1 << 16);
          hi[t*2+1] = h2 | (h3 << 16);
          if (dstLo) {
            const unsigned int l0 = f2bh(y0 - b2f(h0)), l1 = f2bh(y1 - b2f(h1));
            const unsigned int l2 = f2bh(y2 - b2f(h2)), l3 = f2bh(y3 - b2f(h3));
            lo[t*2+0] = l0 | (l1 << 16);
            lo[t*2+1] = l2 | (l3 << 16);
          }
        }
#pragma unroll
        for (int p = 0; p < 3; ++p) {
          const int off = sw192(tok, (ch0 + p * 8) * 2);
          uint4 uh = {hi[p*4+0], hi[p*4+1], hi[p*4+2], hi[p*4+3]};
          *(uint4*)(dstHi + off) = uh;
          if (dstLo) {
            uint4 ul = {lo[p*4+0], lo[p*4+1], lo[p*4+2], lo[p*4+3]};
            *(uint4*)(dstLo + off) = ul;
          }
        }
      };
      doLN(xa_in, nwa, nba, R0, R2);
      doLN(xb_in, nwb, nbb, R1, nullptr);
    } else { // zero pad rows 49..63
      const uint4 z = {0u, 0u, 0u, 0u};
#pragma unroll
      for (int p = 0; p < 3; ++p) {
        const int off = sw192(tok, (ch0 + p * 8) * 2);
        *(uint4*)(R0 + off) = z; *(uint4*)(R1 + off) = z; *(uint4*)(R2 + off) = z;
      }
    }
  }
  __syncthreads(); // barA

  // ---------------- Phase B: QKV GEMMs (n-split across waves) --------------
  // n-tiles 0..5: k (from xa) | 6..11: v hi/lo-split (xa,xa_lo) | 12..17: q (xb)
  {
    const float* bias = (const float*)(ws + BIAS_OFF);
    f32x4 acc[5][4];
#pragma unroll
    for (int i = 0; i < 5; ++i) {
      const int nt = w + 4 * i;
      const float bv = (nt < 18) ? bias[nt * 16 + l15] : 0.f;
      const f32x4 bvv = {bv, bv, bv, bv};
#pragma unroll
      for (int m = 0; m < 4; ++m) acc[i][m] = bvv; // bias as acc-init
    }

    const unsigned char* wqkv = ws + WQKV_OFF;
    const unsigned char* wvlo = ws + WVLO_OFF;

    for (int kt = 0; kt < 3; ++kt) {
      bf16x8 axa[4], axb[4], axlo[4];
      const int abyte = kt * 64 + lg * 16;
#pragma unroll
      for (int mt = 0; mt < 4; ++mt) {
        const int row = mt * 16 + l15;
        const int off = sw192(row, abyte);
        axa[mt]  = *(const bf16x8*)(R0 + off);
        axb[mt]  = *(const bf16x8*)(R1 + off);
        axlo[mt] = *(const bf16x8*)(R2 + off);
      }
#pragma unroll
      for (int i = 0; i < 5; ++i) {
        const int nt = w + 4 * i;
        if (nt < 18) {
          const bf16x8 bw_ = *(const bf16x8*)(wqkv + ((nt * 3 + kt) * 64 + l) * 16);
          if (nt >= 6 && nt < 12) { // v: hi/lo split
            const bf16x8 bl = *(const bf16x8*)(wvlo + (((nt - 6) * 3 + kt) * 64 + l) * 16);
#pragma unroll
            for (int mt = 0; mt < 4; ++mt) {
              acc[i][mt] = __builtin_amdgcn_mfma_f32_16x16x32_bf16(axa[mt],  bw_, acc[i][mt], 0, 0, 0);
              acc[i][mt] = __builtin_amdgcn_mfma_f32_16x16x32_bf16(axlo[mt], bw_, acc[i][mt], 0, 0, 0);
              acc[i][mt] = __builtin_amdgcn_mfma_f32_16x16x32_bf16(axa[mt],  bl,  acc[i][mt], 0, 0, 0);
            }
          } else if (nt >= 12) { // q from xb
#pragma unroll
            for (int mt = 0; mt < 4; ++mt)
              acc[i][mt] = __builtin_amdgcn_mfma_f32_16x16x32_bf16(axb[mt], bw_, acc[i][mt], 0, 0, 0);
          } else { // k from xa
#pragma unroll
            for (int mt = 0; mt < 4; ++mt)
              acc[i][mt] = __builtin_amdgcn_mfma_f32_16x16x32_bf16(axa[mt], bw_, acc[i][mt], 0, 0, 0);
          }
        }
      }
    }
    __syncthreads(); // bar1: all Phase-B LDS reads done; xa/xb/xlo now dead

    // K rows -> R0 (over xa). C/D: col=l&15, row=lg*4+r
#pragma unroll
    for (int i = 0; i < 5; ++i) {
      const int nt = w + 4 * i;
      if (nt < 6) {
        const int col = nt * 16 + l15;
#pragma unroll
        for (int mt = 0; mt < 4; ++mt)
#pragma unroll
          for (int r = 0; r < 4; ++r) {
            const int row = mt * 16 + lg * 4 + r;
            *(unsigned short*)(R0 + sw192(row, col * 2)) = (unsigned short)f2bh(acc[i][mt][r]);
          }
      }
    }
    // Q rows -> R1 (over xb)
#pragma unroll
    for (int i = 0; i < 5; ++i) {
      const int nt = w + 4 * i;
      if (nt >= 12 && nt < 18) {
        const int col = (nt - 12) * 16 + l15;
#pragma unroll
        for (int mt = 0; mt < 4; ++mt)
#pragma unroll
          for (int r = 0; r < 4; ++r) {
            const int row = mt * 16 + lg * 4 + r;
            *(unsigned short*)(R1 + sw192(row, col * 2)) = (unsigned short)f2bh(acc[i][mt][r]);
          }
      }
    }
    // v -> R2 (over xa_lo), NATURAL key order: vT[dim][key]
#pragma unroll
    for (int i = 0; i < 5; ++i) {
      const int nt = w + 4 * i;
      if (nt >= 6 && nt < 12) {
        const int dim = (nt - 6) * 16 + l15;
#pragma unroll
        for (int mt = 0; mt < 4; ++mt) {
          const int key0 = mt * 16 + lg * 4;
          const unsigned int u0 = f2bh(acc[i][mt][0]) | (f2bh(acc[i][mt][1]) << 16);
          const unsigned int u1 = f2bh(acc[i][mt][2]) | (f2bh(acc[i][mt][3]) << 16);
          uint2 u = {u0, u1};
          *(uint2*)(R2 + ((dim * 128 + key0 * 2) ^ ((dim & 7) << 4))) = u;
        }
      }
    }
  }
  __syncthreads(); // bar2: K, Q, vT visible

  // --------- Phase C+D+E fused: swapped QK^T, in-lane softmax, LDS relayout
  // Lane owns q-row (w*16+l15); keys mt*16+lg*4+r live in lg-groups.
  f32x4 po[6];
  {
    const float* bias = (const float*)(ws + BIAS_OFF);
#pragma unroll
    for (int nt = 0; nt < 6; ++nt) {
      const float bv = bias[288 + nt * 16 + l15];
      po[nt] = {bv, bv, bv, bv}; // proj bias as acc-init
    }

    const unsigned short* rpe = (const unsigned short*)(ws + RPE_OFF);
    const int qrow = w * 16 + l15;
    const int qsz  = (qrow & 7) << 4;

    // prefetch all 12 RPE uint2 (rpe3[h][qrow][lg][mt][0..3])
    uint2 rp[3][4];
#pragma unroll
    for (int h = 0; h < 3; ++h)
#pragma unroll
      for (int mt = 0; mt < 4; ++mt)
        rp[h][mt] = *(const uint2*)(rpe + (h * 4096 + qrow * 64 + lg * 16 + mt * 4));

    const unsigned char* wp = ws + WPRJ_OFF;

#pragma unroll
    for (int h = 0; h < 3; ++h) {
      // S^T = K x Q^T : one K=32 MFMA per 16-key tile
      const bf16x8 qB = *(const bf16x8*)(R1 + sw192(qrow, h * 64 + lg * 16));
      f32x4 sT[4];
#pragma unroll
      for (int mt = 0; mt < 4; ++mt) {
        const bf16x8 kA = *(const bf16x8*)(R0 + sw192(mt * 16 + l15, h * 64 + lg * 16));
        sT[mt] = __builtin_amdgcn_mfma_f32_16x16x32_bf16(kA, qB, zf, 0, 0, 0);
      }
      // in-lane softmax over 16 keys + 2 cross-lg shfls
      float e[16];
#pragma unroll
      for (int mt = 0; mt < 4; ++mt) {
        const uint2 u = rp[h][mt];
        e[mt*4+0] = sT[mt][0] + b2f(u.x & 0xffffu);
        e[mt*4+1] = sT[mt][1] + b2f(u.x >> 16);
        e[mt*4+2] = sT[mt][2] + b2f(u.y & 0xffffu);
        e[mt*4+3] = sT[mt][3] + b2f(u.y >> 16);
      }
      float mx = e[0];
#pragma unroll
      for (int i = 1; i < 16; ++i) mx = fmaxf(mx, e[i]);
      mx = fmaxf(mx, __shfl_xor(mx, 16));
      mx = fmaxf(mx, __shfl_xor(mx, 32));
      float sm = 0.f;
#pragma unroll
      for (int i = 0; i < 16; ++i) { e[i] = __expf(e[i] - mx); sm += e[i]; }
      sm += __shfl_xor(sm, 16);
      sm += __shfl_xor(sm, 32);
      const float inv = __fdividef(1.f, sm); // applied to O after PV (f32)

      // store unnormalized P^T slice to PB[qrow][key] (wave-local rows)
#pragma unroll
      for (int mt = 0; mt < 4; ++mt) {
        uint2 u;
        u.x = f2bh(e[mt*4+0]) | (f2bh(e[mt*4+1]) << 16);
        u.y = f2bh(e[mt*4+2]) | (f2bh(e[mt*4+3]) << 16);
        *(uint2*)(PB + ((qrow * 128 + mt * 32 + lg * 8) ^ qsz)) = u;
      }

      // PV: O^T[dim][qrow] = sum_key vT[dim][key] P^T[key][qrow]
      f32x4 od0 = zf, od1 = zf;
      const int d0 = h * 32 + l15;
      const int d1 = d0 + 16;
#pragma unroll
      for (int blk = 0; blk < 2; ++blk) {
        const bf16x8 pf = *(const bf16x8*)(PB + ((qrow * 128 + blk * 64 + lg * 16) ^ qsz));
        const bf16x8 v0 = *(const bf16x8*)(R2 + ((d0 * 128 + blk * 64 + lg * 16) ^ ((d0 & 7) << 4)));
        const bf16x8 v1 = *(const bf16x8*)(R2 + ((d1 * 128 + blk * 64 + lg * 16) ^ ((d1 & 7) << 4)));
        od0 = __builtin_amdgcn_mfma_f32_16x16x32_bf16(v0, pf, od0, 0, 0, 0);
        od1 = __builtin_amdgcn_mfma_f32_16x16x32_bf16(v1, pf, od1, 0, 0, 0);
      }

      // normalize in f32; stage O slice in OB[qrow][dim-local] (wave-local)
      {
        uint2 o0p, o1p;
        o0p.x = f2bh(od0[0] * inv) | (f2bh(od0[1] * inv) << 16);
        o0p.y = f2bh(od0[2] * inv) | (f2bh(od0[3] * inv) << 16);
        o1p.x = f2bh(od1[0] * inv) | (f2bh(od1[1] * inv) << 16);
        o1p.y = f2bh(od1[2] * inv) | (f2bh(od1[3] * inv) << 16);
        *(uint2*)(OB + ((qrow * 128 +      lg * 8) ^ qsz)) = o0p;
        *(uint2*)(OB + ((qrow * 128 + 32 + lg * 8) ^ qsz)) = o1p;
      }
      const bf16x8 af = *(const bf16x8*)(OB + ((qrow * 128 + lg * 16) ^ qsz));

      // proj accumulation for kt = h
#pragma unroll
      for (int nt = 0; nt < 6; ++nt) {
        const bf16x8 bp = *(const bf16x8*)(wp + ((nt * 3 + h) * 64 + l) * 16);
        po[nt] = __builtin_amdgcn_mfma_f32_16x16x32_bf16(af, bp, po[nt], 0, 0, 0);
      }
    }
  }
  __syncthreads(); // barX: all waves done reading K/Q (R0/R1) before stage

  // ---------------- stage fp32 result over R0+R1 ---------------------------
  {
#pragma unroll
    for (int nt = 0; nt < 6; ++nt) {
#pragma unroll
      for (int r = 0; r < 4; ++r) {
        const int row = w * 16 + lg * 4 + r;
        if (row < 49)
          *(float*)(smem + sw384(row, (nt * 16 + l15) * 4)) = po[nt][r];
      }
    }
  }
  __syncthreads(); // bar7: out-stage read cross-wave below

  // ---------------- Final: coalesced float4 store (window_reverse) ---------
  {
    for (int i = tid; i < 49 * 24; i += 256) {
      const int tok = i / 24;
      const int cg  = i - tok * 24;
      const float4 v = *(const float4*)(smem + sw384(tok, cg * 16));
      float* dst = out + (long)(pixbase + (tok / 7) * 224 + (tok % 7)) * 96 + cg * 4;
      *(float4*)dst = v;
    }
  }
}

extern "C" void kernel_launch(void* const* d_in, const int* in_sizes, int n_in,
                              void* d_out, int out_size, void* d_ws, size_t ws_size,
                              hipStream_t stream)
{
  const float* rescaled  = (const float*)d_in[0];
  const float* rescaler  = (const float*)d_in[1];
  const float* norm_w_a  = (const float*)d_in[2];
  const float* norm_b_a  = (const float*)d_in[3];
  const float* norm_w_b  = (const float*)d_in[4];
  const float* norm_b_b  = (const float*)d_in[5];
  const float* qkv_w_a   = (const float*)d_in[6];
  const float* qkv_b_a   = (const float*)d_in[7];
  const float* qkv_w_b   = (const float*)d_in[8];
  const float* qkv_b_b   = (const float*)d_in[9];
  const float* rpe_table = (const float*)d_in[10];
  const float* proj_w    = (const float*)d_in[11];
  const float* proj_b    = (const float*)d_in[12];
  const int*   rpe_index = (const int*)d_in[13];
  unsigned char* ws = (unsigned char*)d_ws;
  float* outp = (float*)d_out;

  hipLaunchKernelGGL(prepack_kernel, dim3(64), dim3(256), 0, stream,
                     qkv_w_a, qkv_b_a, qkv_w_b, qkv_b_b, rpe_table, proj_w,
                     proj_b, rpe_index, ws);
  hipLaunchKernelGGL(swin_main, dim3(8192), dim3(256), 0, stream,
                     rescaled, rescaler, norm_w_a, norm_b_a, norm_w_b, norm_b_b,
                     ws, outp);
}

// Round 8
// 228.779 us; speedup vs baseline: 2.1336x; 1.0185x over previous
//
#include <hip/hip_runtime.h>
#include <hip/hip_bf16.h>

#define DI __device__ __forceinline__

typedef __bf16 bf16x8 __attribute__((ext_vector_type(8)));
typedef float f32x4 __attribute__((ext_vector_type(4)));

constexpr float SCALE_Q = 0.17677669529663687f; // 32^-0.5

// workspace byte offsets
constexpr int WQKV_OFF = 0;       // 27648 bf16 = 55296 B  (18 n-tiles x 3 k-iters x 64 lanes x 8)
constexpr int WVLO_OFF = 55296;   //  9216 bf16 = 18432 B  (Wv lo-part fragments)
constexpr int WPRJ_OFF = 73728;   //  9216 bf16 = 18432 B
constexpr int BIAS_OFF = 92160;   //   384 f32  = 1536 B   ([k 0:96][v 96:192][q 192:288][proj 288:384])
constexpr int RPE_OFF  = 93696;   // 12288 bf16 = 24576 B  (rpe3[h][qrow 64][lg 4][mt 4][r 4], key=mt*16+lg*4+r)
// total 118272 B

DI unsigned int f2b(float x) {  // float -> bf16 bits, RNE (software; prepack only)
  union { float f; unsigned int u; } v; v.f = x;
  return (v.u + 0x7fffu + ((v.u >> 16) & 1u)) >> 16;
}
DI unsigned int f2bh(float x) { // float -> bf16 bits via HW cvt (RNE)
  union { __bf16 b; unsigned short u; } v;
  v.b = (__bf16)x;
  return (unsigned int)v.u;
}
DI float b2f(unsigned int u) {
  union { unsigned int u; float f; } v; v.u = u << 16;
  return v.f;
}
DI int sw192(int row, int bytecol) { return (row * 192 + bytecol) ^ ((row & 7) << 4); }

// ---------------------------------------------------------------------------
// Prepack: fragment-ordered bf16 weights (+Wv lo split), biases, gathered RPE.
// B-fragment layout for mfma_f32_16x16x32_bf16: lane l, elem j holds
// B[k = kt*32 + (l>>4)*8 + j][n = nt*16 + (l&15)].
// ---------------------------------------------------------------------------
__global__ void prepack_kernel(const float* __restrict__ qkv_w_a,
                               const float* __restrict__ qkv_b_a,
                               const float* __restrict__ qkv_w_b,
                               const float* __restrict__ qkv_b_b,
                               const float* __restrict__ rpe_table,
                               const float* __restrict__ proj_w,
                               const float* __restrict__ proj_b,
                               const int* __restrict__ rpe_index,
                               unsigned char* __restrict__ ws)
{
  unsigned short* wqkv = (unsigned short*)(ws + WQKV_OFF);
  unsigned short* wvlo = (unsigned short*)(ws + WVLO_OFF);
  unsigned short* wprj = (unsigned short*)(ws + WPRJ_OFF);
  float* bias          = (float*)(ws + BIAS_OFF);
  unsigned short* rpe  = (unsigned short*)(ws + RPE_OFF);

  const int total = 27648 + 9216 + 9216 + 384 + 12288;
  for (int idx = blockIdx.x * blockDim.x + threadIdx.x; idx < total;
       idx += gridDim.x * blockDim.x) {
    int i = idx;
    if (i < 27648) { // [Wk | Wv_hi | Wq*scale] fragments
      const int j = i & 7, lane = (i >> 3) & 63, t = i >> 9;
      const int kt = t % 3, nt = t / 3;
      const int k = kt * 32 + (lane >> 4) * 8 + j, c = lane & 15;
      float v;
      if (nt < 12) v = qkv_w_a[k * 288 + 96 + nt * 16 + c];      // Wk then Wv (cols 96..287)
      else         v = qkv_w_b[k * 288 + (nt - 12) * 16 + c] * SCALE_Q;
      wqkv[i] = (unsigned short)f2b(v);
    } else if ((i -= 27648) < 9216) { // Wv lo-part
      const int j = i & 7, lane = (i >> 3) & 63, t = i >> 9;
      const int kt = t % 3, vnt = t / 3;
      const int k = kt * 32 + (lane >> 4) * 8 + j, c = lane & 15;
      const float full = qkv_w_a[k * 288 + 192 + vnt * 16 + c];
      const unsigned int hi = f2b(full);
      wvlo[i] = (unsigned short)f2b(full - b2f(hi));
    } else if ((i -= 9216) < 9216) { // proj_w
      const int j = i & 7, lane = (i >> 3) & 63, t = i >> 9;
      const int kt = t % 3, nt = t / 3;
      const int k = kt * 32 + (lane >> 4) * 8 + j, c = lane & 15;
      wprj[i] = (unsigned short)f2b(proj_w[k * 96 + nt * 16 + c]);
    } else if ((i -= 9216) < 384) { // biases
      float v;
      if (i < 192)      v = qkv_b_a[96 + i];           // k then v biases
      else if (i < 288) v = qkv_b_b[i - 192] * SCALE_Q; // q bias * scale
      else              v = proj_b[i - 288];
      bias[i] = v;
    } else { // rpe3 [h][qrow][lg][mt][r]: value = rpe(h, qrow, key=mt*16+lg*4+r)
      i -= 384;
      const int h = i >> 12, rest = i & 4095;
      const int qrow = rest >> 6, lg = (rest >> 4) & 3, mt = (rest >> 2) & 3, r = i & 3;
      const int key = mt * 16 + lg * 4 + r;
      float v;
      if (key >= 49)       v = -1e30f;
      else if (qrow >= 49) v = 0.f;
      else                 v = rpe_table[h * 169 + rpe_index[qrow * 49 + key]];
      rpe[i] = (unsigned short)f2b(v);
    }
  }
}

// ---------------------------------------------------------------------------
// Fused main kernel: one 7x7 window per 256-thread block (4 waves).
// LDS: 3 regions x 12 KB + PB 8 KB + OB 8 KB = 53248 B (3 blocks/CU).
//   R0 @0     : xa_hi -> K
//   R1 @12288 : xb    -> Q
//   R2 @24576 : xa_lo -> vT  (natural key order)
//   PB @36864 : wave-local P^T staging [64 qrow][64 key] bf16, swz (qrow&7)<<4
//   OB @45056 : wave-local O staging   [64 qrow][64 B]     , swz (qrow&7)<<4
// Swapped-operand S^T = K x Q^T: each lane owns one q-row; softmax in-lane +
// 2 shfls; P/O fragment relayouts via wave-local LDS (same-wave DS ordered).
// Epilogue: proj accumulators stored DIRECTLY to global (no out-stage, no
// barriers after bar2) — 64B-contiguous segments per (nt,r), full lines dirty.
// ---------------------------------------------------------------------------
__global__ __launch_bounds__(256, 3)
void swin_main(const float* __restrict__ xa_in, const float* __restrict__ xb_in,
               const float* __restrict__ nwa, const float* __restrict__ nba,
               const float* __restrict__ nwb, const float* __restrict__ nbb,
               const unsigned char* __restrict__ ws, float* __restrict__ out)
{
  __shared__ unsigned char smem[53248];
  unsigned char* const R0 = smem;
  unsigned char* const R1 = smem + 12288;
  unsigned char* const R2 = smem + 24576;
  unsigned char* const PB = smem + 36864;
  unsigned char* const OB = smem + 45056;

  const int tid = threadIdx.x;
  const int w   = tid >> 6;   // wave id 0..3
  const int l   = tid & 63;
  const int l15 = l & 15;
  const int lg  = l >> 4;

  const int bw  = blockIdx.x;
  const int bb  = bw >> 10;
  const int hwi = (bw >> 5) & 31;
  const int wwi = bw & 31;
  const int pixbase = (bb * 224 + hwi * 7) * 224 + wwi * 7;

  const f32x4 zf = {0.f, 0.f, 0.f, 0.f};

  // ---------------- Phase A: load + LayerNorm -> bf16 (hi/lo for xa) -------
  {
    const int tok = tid >> 2;
    const int j   = tid & 3;
    const int ch0 = j * 24;
    if (tok < 49) {
      const int gbase = (pixbase + (tok / 7) * 224 + (tok % 7)) * 96 + ch0;
      auto doLN = [&](const float* __restrict__ xin, const float* __restrict__ gw,
                      const float* __restrict__ gb, unsigned char* dstHi,
                      unsigned char* dstLo) {
        float x[24];
        float s = 0.f, s2 = 0.f;
#pragma unroll
        for (int t = 0; t < 6; ++t) {
          const float4 v = *(const float4*)(xin + gbase + t * 4);
          x[t*4+0] = v.x; x[t*4+1] = v.y; x[t*4+2] = v.z; x[t*4+3] = v.w;
          s  += v.x + v.y + v.z + v.w;
          s2 += v.x*v.x + v.y*v.y + v.z*v.z + v.w*v.w;
        }
        s += __shfl_xor(s, 1);  s2 += __shfl_xor(s2, 1);
        s += __shfl_xor(s, 2);  s2 += __shfl_xor(s2, 2);
        const float mu = s * (1.f / 96.f);
        const float rs = rsqrtf(s2 * (1.f / 96.f) - mu * mu + 1e-5f);
        unsigned int hi[12], lo[12];
#pragma unroll
        for (int t = 0; t < 6; ++t) {
          const float4 g  = *(const float4*)(gw + ch0 + t * 4);
          const float4 be = *(const float4*)(gb + ch0 + t * 4);
          const float y0 = (x[t*4+0] - mu) * rs * g.x + be.x;
          const float y1 = (x[t*4+1] - mu) * rs * g.y + be.y;
          const float y2 = (x[t*4+2] - mu) * rs * g.z + be.z;
          const float y3 = (x[t*4+3] - mu) * rs * g.w + be.w;
          const unsigned int h0 = f2bh(y0), h1 = f2bh(y1), h2 = f2bh(y2), h3 = f2bh(y3);
          hi[t*2+0] = h0 | (h1 << 16);
          hi[t*2+1] = h2 | (h3 << 16);
          if (dstLo) {
            const unsigned int l0 = f2bh(y0 - b2f(h0)), l1 = f2bh(y1 - b2f(h1));
            const unsigned int l2 = f2bh(y2 - b2f(h2)), l3 = f2bh(y3 - b2f(h3));
            lo[t*2+0] = l0 | (l1 << 16);
            lo[t*2+1] = l2 | (l3 << 16);
          }
        }
#pragma unroll
        for (int p = 0; p < 3; ++p) {
          const int off = sw192(tok, (ch0 + p * 8) * 2);
          uint4 uh = {hi[p*4+0], hi[p*4+1], hi[p*4+2], hi[p*4+3]};
          *(uint4*)(dstHi + off) = uh;
          if (dstLo) {
            uint4 ul = {lo[p*4+0], lo[p*4+1], lo[p*4+2], lo[p*4+3]};
            *(uint4*)(dstLo + off) = ul;
          }
        }
      };
      doLN(xa_in, nwa, nba, R0, R2);
      doLN(xb_in, nwb, nbb, R1, nullptr);
    } else { // zero pad rows 49..63
      const uint4 z = {0u, 0u, 0u, 0u};
#pragma unroll
      for (int p = 0; p < 3; ++p) {
        const int off = sw192(tok, (ch0 + p * 8) * 2);
        *(uint4*)(R0 + off) = z; *(uint4*)(R1 + off) = z; *(uint4*)(R2 + off) = z;
      }
    }
  }
  __syncthreads(); // barA

  // ---------------- Phase B: QKV GEMMs (n-split across waves) --------------
  // n-tiles 0..5: k (from xa) | 6..11: v hi/lo-split (xa,xa_lo) | 12..17: q (xb)
  {
    const float* bias = (const float*)(ws + BIAS_OFF);
    f32x4 acc[5][4];
#pragma unroll
    for (int i = 0; i < 5; ++i) {
      const int nt = w + 4 * i;
      const float bv = (nt < 18) ? bias[nt * 16 + l15] : 0.f;
      const f32x4 bvv = {bv, bv, bv, bv};
#pragma unroll
      for (int m = 0; m < 4; ++m) acc[i][m] = bvv; // bias as acc-init
    }

    const unsigned char* wqkv = ws + WQKV_OFF;
    const unsigned char* wvlo = ws + WVLO_OFF;

    for (int kt = 0; kt < 3; ++kt) {
      bf16x8 axa[4], axb[4], axlo[4];
      const int abyte = kt * 64 + lg * 16;
#pragma unroll
      for (int mt = 0; mt < 4; ++mt) {
        const int row = mt * 16 + l15;
        const int off = sw192(row, abyte);
        axa[mt]  = *(const bf16x8*)(R0 + off);
        axb[mt]  = *(const bf16x8*)(R1 + off);
        axlo[mt] = *(const bf16x8*)(R2 + off);
      }
#pragma unroll
      for (int i = 0; i < 5; ++i) {
        const int nt = w + 4 * i;
        if (nt < 18) {
          const bf16x8 bw_ = *(const bf16x8*)(wqkv + ((nt * 3 + kt) * 64 + l) * 16);
          if (nt >= 6 && nt < 12) { // v: hi/lo split
            const bf16x8 bl = *(const bf16x8*)(wvlo + (((nt - 6) * 3 + kt) * 64 + l) * 16);
#pragma unroll
            for (int mt = 0; mt < 4; ++mt) {
              acc[i][mt] = __builtin_amdgcn_mfma_f32_16x16x32_bf16(axa[mt],  bw_, acc[i][mt], 0, 0, 0);
              acc[i][mt] = __builtin_amdgcn_mfma_f32_16x16x32_bf16(axlo[mt], bw_, acc[i][mt], 0, 0, 0);
              acc[i][mt] = __builtin_amdgcn_mfma_f32_16x16x32_bf16(axa[mt],  bl,  acc[i][mt], 0, 0, 0);
            }
          } else if (nt >= 12) { // q from xb
#pragma unroll
            for (int mt = 0; mt < 4; ++mt)
              acc[i][mt] = __builtin_amdgcn_mfma_f32_16x16x32_bf16(axb[mt], bw_, acc[i][mt], 0, 0, 0);
          } else { // k from xa
#pragma unroll
            for (int mt = 0; mt < 4; ++mt)
              acc[i][mt] = __builtin_amdgcn_mfma_f32_16x16x32_bf16(axa[mt], bw_, acc[i][mt], 0, 0, 0);
          }
        }
      }
    }
    __syncthreads(); // bar1: all Phase-B LDS reads done; xa/xb/xlo now dead

    // K rows -> R0 (over xa). C/D: col=l&15, row=lg*4+r
#pragma unroll
    for (int i = 0; i < 5; ++i) {
      const int nt = w + 4 * i;
      if (nt < 6) {
        const int col = nt * 16 + l15;
#pragma unroll
        for (int mt = 0; mt < 4; ++mt)
#pragma unroll
          for (int r = 0; r < 4; ++r) {
            const int row = mt * 16 + lg * 4 + r;
            *(unsigned short*)(R0 + sw192(row, col * 2)) = (unsigned short)f2bh(acc[i][mt][r]);
          }
      }
    }
    // Q rows -> R1 (over xb)
#pragma unroll
    for (int i = 0; i < 5; ++i) {
      const int nt = w + 4 * i;
      if (nt >= 12 && nt < 18) {
        const int col = (nt - 12) * 16 + l15;
#pragma unroll
        for (int mt = 0; mt < 4; ++mt)
#pragma unroll
          for (int r = 0; r < 4; ++r) {
            const int row = mt * 16 + lg * 4 + r;
            *(unsigned short*)(R1 + sw192(row, col * 2)) = (unsigned short)f2bh(acc[i][mt][r]);
          }
      }
    }
    // v -> R2 (over xa_lo), NATURAL key order: vT[dim][key]
#pragma unroll
    for (int i = 0; i < 5; ++i) {
      const int nt = w + 4 * i;
      if (nt >= 6 && nt < 12) {
        const int dim = (nt - 6) * 16 + l15;
#pragma unroll
        for (int mt = 0; mt < 4; ++mt) {
          const int key0 = mt * 16 + lg * 4;
          const unsigned int u0 = f2bh(acc[i][mt][0]) | (f2bh(acc[i][mt][1]) << 16);
          const unsigned int u1 = f2bh(acc[i][mt][2]) | (f2bh(acc[i][mt][3]) << 16);
          uint2 u = {u0, u1};
          *(uint2*)(R2 + ((dim * 128 + key0 * 2) ^ ((dim & 7) << 4))) = u;
        }
      }
    }
  }
  __syncthreads(); // bar2: K, Q, vT visible (LAST barrier)

  // --------- Phase C+D+E fused: swapped QK^T, in-lane softmax, LDS relayout
  // Lane owns q-row (w*16+l15); keys mt*16+lg*4+r live in lg-groups.
  f32x4 po[6];
  {
    const float* bias = (const float*)(ws + BIAS_OFF);
#pragma unroll
    for (int nt = 0; nt < 6; ++nt) {
      const float bv = bias[288 + nt * 16 + l15];
      po[nt] = {bv, bv, bv, bv}; // proj bias as acc-init
    }

    const unsigned short* rpe = (const unsigned short*)(ws + RPE_OFF);
    const int qrow = w * 16 + l15;
    const int qsz  = (qrow & 7) << 4;

    // prefetch all 12 RPE uint2 (rpe3[h][qrow][lg][mt][0..3])
    uint2 rp[3][4];
#pragma unroll
    for (int h = 0; h < 3; ++h)
#pragma unroll
      for (int mt = 0; mt < 4; ++mt)
        rp[h][mt] = *(const uint2*)(rpe + (h * 4096 + qrow * 64 + lg * 16 + mt * 4));

    const unsigned char* wp = ws + WPRJ_OFF;

#pragma unroll
    for (int h = 0; h < 3; ++h) {
      // S^T = K x Q^T : one K=32 MFMA per 16-key tile
      const bf16x8 qB = *(const bf16x8*)(R1 + sw192(qrow, h * 64 + lg * 16));
      f32x4 sT[4];
#pragma unroll
      for (int mt = 0; mt < 4; ++mt) {
        const bf16x8 kA = *(const bf16x8*)(R0 + sw192(mt * 16 + l15, h * 64 + lg * 16));
        sT[mt] = __builtin_amdgcn_mfma_f32_16x16x32_bf16(kA, qB, zf, 0, 0, 0);
      }
      // in-lane softmax over 16 keys + 2 cross-lg shfls
      float e[16];
#pragma unroll
      for (int mt = 0; mt < 4; ++mt) {
        const uint2 u = rp[h][mt];
        e[mt*4+0] = sT[mt][0] + b2f(u.x & 0xffffu);
        e[mt*4+1] = sT[mt][1] + b2f(u.x >> 16);
        e[mt*4+2] = sT[mt][2] + b2f(u.y & 0xffffu);
        e[mt*4+3] = sT[mt][3] + b2f(u.y >> 16);
      }
      float mx = e[0];
#pragma unroll
      for (int i = 1; i < 16; ++i) mx = fmaxf(mx, e[i]);
      mx = fmaxf(mx, __shfl_xor(mx, 16));
      mx = fmaxf(mx, __shfl_xor(mx, 32));
      float sm = 0.f;
#pragma unroll
      for (int i = 0; i < 16; ++i) { e[i] = __expf(e[i] - mx); sm += e[i]; }
      sm += __shfl_xor(sm, 16);
      sm += __shfl_xor(sm, 32);
      const float inv = __fdividef(1.f, sm); // applied to O after PV (f32)

      // store unnormalized P^T slice to PB[qrow][key] (wave-local rows)
#pragma unroll
      for (int mt = 0; mt < 4; ++mt) {
        uint2 u;
        u.x = f2bh(e[mt*4+0]) | (f2bh(e[mt*4+1]) << 16);
        u.y = f2bh(e[mt*4+2]) | (f2bh(e[mt*4+3]) << 16);
        *(uint2*)(PB + ((qrow * 128 + mt * 32 + lg * 8) ^ qsz)) = u;
      }

      // PV: O^T[dim][qrow] = sum_key vT[dim][key] P^T[key][qrow]
      f32x4 od0 = zf, od1 = zf;
      const int d0 = h * 32 + l15;
      const int d1 = d0 + 16;
#pragma unroll
      for (int blk = 0; blk < 2; ++blk) {
        const bf16x8 pf = *(const bf16x8*)(PB + ((qrow * 128 + blk * 64 + lg * 16) ^ qsz));
        const bf16x8 v0 = *(const bf16x8*)(R2 + ((d0 * 128 + blk * 64 + lg * 16) ^ ((d0 & 7) << 4)));
        const bf16x8 v1 = *(const bf16x8*)(R2 + ((d1 * 128 + blk * 64 + lg * 16) ^ ((d1 & 7) << 4)));
        od0 = __builtin_amdgcn_mfma_f32_16x16x32_bf16(v0, pf, od0, 0, 0, 0);
        od1 = __builtin_amdgcn_mfma_f32_16x16x32_bf16(v1, pf, od1, 0, 0, 0);
      }

      // normalize in f32; stage O slice in OB[qrow][dim-local] (wave-local)
      {
        uint2 o0p, o1p;
        o0p.x = f2bh(od0[0] * inv) | (f2bh(od0[1] * inv) << 16);
        o0p.y = f2bh(od0[2] * inv) | (f2bh(od0[3] * inv) << 16);
        o1p.x = f2bh(od1[0] * inv) | (f2bh(od1[1] * inv) << 16);
        o1p.y = f2bh(od1[2] * inv) | (f2bh(od1[3] * inv) << 16);
        *(uint2*)(OB + ((qrow * 128 +      lg * 8) ^ qsz)) = o0p;
        *(uint2*)(OB + ((qrow * 128 + 32 + lg * 8) ^ qsz)) = o1p;
      }
      const bf16x8 af = *(const bf16x8*)(OB + ((qrow * 128 + lg * 16) ^ qsz));

      // proj accumulation for kt = h
#pragma unroll
      for (int nt = 0; nt < 6; ++nt) {
        const bf16x8 bp = *(const bf16x8*)(wp + ((nt * 3 + h) * 64 + l) * 16);
        po[nt] = __builtin_amdgcn_mfma_f32_16x16x32_bf16(af, bp, po[nt], 0, 0, 0);
      }
    }
  }

  // ---------------- Epilogue: DIRECT global stores (no barriers) -----------
  // po[nt][r] -> out[pix(row)*96 + nt*16 + l15], row = w*16+lg*4+r.
  // For fixed (nt,r): 4 rows x 16 lanes x 4B = 64B-contiguous segments.
  {
#pragma unroll
    for (int r = 0; r < 4; ++r) {
      const int row = w * 16 + lg * 4 + r;
      if (row < 49) {
        const int pix = pixbase + (row / 7) * 224 + (row % 7);
        float* dst = out + (long)pix * 96 + l15;
#pragma unroll
        for (int nt = 0; nt < 6; ++nt)
          dst[nt * 16] = po[nt][r];
      }
    }
  }
}

extern "C" void kernel_launch(void* const* d_in, const int* in_sizes, int n_in,
                              void* d_out, int out_size, void* d_ws, size_t ws_size,
                              hipStream_t stream)
{
  const float* rescaled  = (const float*)d_in[0];
  const float* rescaler  = (const float*)d_in[1];
  const float* norm_w_a  = (const float*)d_in[2];
  const float* norm_b_a  = (const float*)d_in[3];
  const float* norm_w_b  = (const float*)d_in[4];
  const float* norm_b_b  = (const float*)d_in[5];
  const float* qkv_w_a   = (const float*)d_in[6];
  const float* qkv_b_a   = (const float*)d_in[7];
  const float* qkv_w_b   = (const float*)d_in[8];
  const float* qkv_b_b   = (const float*)d_in[9];
  const float* rpe_table = (const float*)d_in[10];
  const float* proj_w    = (const float*)d_in[11];
  const float* proj_b    = (const float*)d_in[12];
  const int*   rpe_index = (const int*)d_in[13];
  unsigned char* ws = (unsigned char*)d_ws;
  float* outp = (float*)d_out;

  hipLaunchKernelGGL(prepack_kernel, dim3(64), dim3(256), 0, stream,
                     qkv_w_a, qkv_b_a, qkv_w_b, qkv_b_b, rpe_table, proj_w,
                     proj_b, rpe_index, ws);
  hipLaunchKernelGGL(swin_main, dim3(8192), dim3(256), 0, stream,
                     rescaled, rescaler, norm_w_a, norm_b_a, norm_w_b, norm_b_b,
                     ws, outp);
}

// Round 9
// 188.603 us; speedup vs baseline: 2.5881x; 1.2130x over previous
//
#include <hip/hip_runtime.h>
#include <hip/hip_bf16.h>

#define DI __device__ __forceinline__

typedef __bf16 bf16x8 __attribute__((ext_vector_type(8)));
typedef float f32x4 __attribute__((ext_vector_type(4)));

constexpr float SCALE_Q = 0.17677669529663687f; // 32^-0.5

// workspace byte offsets
constexpr int WQKV_OFF = 0;       // 27648 bf16 = 55296 B  (18 n-tiles x 3 k-iters x 64 lanes x 8)
constexpr int WVLO_OFF = 55296;   //  9216 bf16 = 18432 B  (Wv lo-part fragments)
constexpr int WPRJ_OFF = 73728;   //  9216 bf16 = 18432 B
constexpr int BIAS_OFF = 92160;   //   384 f32  = 1536 B   ([k 0:96][v 96:192][q 192:288][proj 288:384])
constexpr int RPE_OFF  = 93696;   // 12288 bf16 = 24576 B  (rpe3[h][qrow 64][lg 4][mt 4][r 4], key=mt*16+lg*4+r)
// total 118272 B

// LDS layout (39296 B total -> 4 blocks/CU):
//   XA/K  @ 0      (49 rows x 192 B = 9408)
//   XB/Q  @ 9408   (9408)
//   XLO/vT@ 18816  (xa_lo: 9408 used; vT: 96 dims x 128 B = 12288)
//   PB/OB @ 31104  (8192, merged: per-head P^T then O, wave-local ordering)
// Rows >=49 of any region read into the next region: finite garbage, masked
// downstream (RPE -1e30 for keys>=49; rows>=49 never stored). Bytes
// [28224,31104) zeroed in phase A so xa_lo garbage reads are never NaN.
constexpr int XA_OFF  = 0;
constexpr int XB_OFF  = 9408;
constexpr int XLO_OFF = 18816;
constexpr int PB_OFF  = 31104;

DI unsigned int f2b(float x) {  // float -> bf16 bits, RNE (software; prepack only)
  union { float f; unsigned int u; } v; v.f = x;
  return (v.u + 0x7fffu + ((v.u >> 16) & 1u)) >> 16;
}
DI unsigned int f2bh(float x) { // float -> bf16 bits via HW cvt (RNE)
  union { __bf16 b; unsigned short u; } v;
  v.b = (__bf16)x;
  return (unsigned int)v.u;
}
DI float b2f(unsigned int u) {
  union { unsigned int u; float f; } v; v.u = u << 16;
  return v.f;
}
DI int sw192(int row, int bytecol) { return (row * 192 + bytecol) ^ ((row & 7) << 4); }

// ---------------------------------------------------------------------------
// Prepack kernel: unchanged from R8.
// ---------------------------------------------------------------------------
__global__ void prepack_kernel(const float* __restrict__ qkv_w_a,
                               const float* __restrict__ qkv_b_a,
                               const float* __restrict__ qkv_w_b,
                               const float* __restrict__ qkv_b_b,
                               const float* __restrict__ rpe_table,
                               const float* __restrict__ proj_w,
                               const float* __restrict__ proj_b,
                               const int* __restrict__ rpe_index,
                               unsigned char* __restrict__ ws)
{
  unsigned short* wqkv = (unsigned short*)(ws + WQKV_OFF);
  unsigned short* wvlo = (unsigned short*)(ws + WVLO_OFF);
  unsigned short* wprj = (unsigned short*)(ws + WPRJ_OFF);
  float* bias          = (float*)(ws + BIAS_OFF);
  unsigned short* rpe  = (unsigned short*)(ws + RPE_OFF);

  const int total = 27648 + 9216 + 9216 + 384 + 12288;
  for (int idx = blockIdx.x * blockDim.x + threadIdx.x; idx < total;
       idx += gridDim.x * blockDim.x) {
    int i = idx;
    if (i < 27648) { // [Wk | Wv_hi | Wq*scale] fragments
      const int j = i & 7, lane = (i >> 3) & 63, t = i >> 9;
      const int kt = t % 3, nt = t / 3;
      const int k = kt * 32 + (lane >> 4) * 8 + j, c = lane & 15;
      float v;
      if (nt < 12) v = qkv_w_a[k * 288 + 96 + nt * 16 + c];
      else         v = qkv_w_b[k * 288 + (nt - 12) * 16 + c] * SCALE_Q;
      wqkv[i] = (unsigned short)f2b(v);
    } else if ((i -= 27648) < 9216) { // Wv lo-part
      const int j = i & 7, lane = (i >> 3) & 63, t = i >> 9;
      const int kt = t % 3, vnt = t / 3;
      const int k = kt * 32 + (lane >> 4) * 8 + j, c = lane & 15;
      const float full = qkv_w_a[k * 288 + 192 + vnt * 16 + c];
      const unsigned int hi = f2b(full);
      wvlo[i] = (unsigned short)f2b(full - b2f(hi));
    } else if ((i -= 9216) < 9216) { // proj_w
      const int j = i & 7, lane = (i >> 3) & 63, t = i >> 9;
      const int kt = t % 3, nt = t / 3;
      const int k = kt * 32 + (lane >> 4) * 8 + j, c = lane & 15;
      wprj[i] = (unsigned short)f2b(proj_w[k * 96 + nt * 16 + c]);
    } else if ((i -= 9216) < 384) { // biases
      float v;
      if (i < 192)      v = qkv_b_a[96 + i];
      else if (i < 288) v = qkv_b_b[i - 192] * SCALE_Q;
      else              v = proj_b[i - 288];
      bias[i] = v;
    } else { // rpe3 [h][qrow][lg][mt][r]: value = rpe(h, qrow, key=mt*16+lg*4+r)
      i -= 384;
      const int h = i >> 12, rest = i & 4095;
      const int qrow = rest >> 6, lg = (rest >> 4) & 3, mt = (rest >> 2) & 3, r = i & 3;
      const int key = mt * 16 + lg * 4 + r;
      float v;
      if (key >= 49)       v = -1e30f;
      else if (qrow >= 49) v = 0.f;
      else                 v = rpe_table[h * 169 + rpe_index[qrow * 49 + key]];
      rpe[i] = (unsigned short)f2b(v);
    }
  }
}

// ---------------------------------------------------------------------------
// Fused main kernel: one 7x7 window per 256-thread block (4 waves),
// 39296 B LDS -> 4 blocks/CU. Phase B is 2-pass to cap registers <=128.
// ---------------------------------------------------------------------------
__global__ __launch_bounds__(256, 4)
void swin_main(const float* __restrict__ xa_in, const float* __restrict__ xb_in,
               const float* __restrict__ nwa, const float* __restrict__ nba,
               const float* __restrict__ nwb, const float* __restrict__ nbb,
               const unsigned char* __restrict__ ws, float* __restrict__ out)
{
  __shared__ unsigned char smem[39296];

  const int tid = threadIdx.x;
  const int w   = tid >> 6;   // wave id 0..3
  const int l   = tid & 63;
  const int l15 = l & 15;
  const int lg  = l >> 4;

  const int bw  = blockIdx.x;
  const int bb  = bw >> 10;
  const int hwi = (bw >> 5) & 31;
  const int wwi = bw & 31;
  const int pixbase = (bb * 224 + hwi * 7) * 224 + wwi * 7;

  const f32x4 zf = {0.f, 0.f, 0.f, 0.f};

  // ---------------- Phase A: load + LayerNorm -> bf16 (hi/lo for xa) -------
  {
    const int tok = tid >> 2;
    const int j   = tid & 3;
    const int ch0 = j * 24;
    if (tok < 49) {
      const int gbase = (pixbase + (tok / 7) * 224 + (tok % 7)) * 96 + ch0;
      // interleaved loads: all 12 float4 loads in flight before compute
      float xa_[24], xb_[24];
#pragma unroll
      for (int t = 0; t < 6; ++t) {
        const float4 va = *(const float4*)(xa_in + gbase + t * 4);
        const float4 vb = *(const float4*)(xb_in + gbase + t * 4);
        xa_[t*4+0] = va.x; xa_[t*4+1] = va.y; xa_[t*4+2] = va.z; xa_[t*4+3] = va.w;
        xb_[t*4+0] = vb.x; xb_[t*4+1] = vb.y; xb_[t*4+2] = vb.z; xb_[t*4+3] = vb.w;
      }
      auto doLN = [&](const float* x, const float* __restrict__ gw,
                      const float* __restrict__ gb, unsigned char* dstHi,
                      unsigned char* dstLo) {
        float s = 0.f, s2 = 0.f;
#pragma unroll
        for (int t = 0; t < 6; ++t) {
          s  += x[t*4+0] + x[t*4+1] + x[t*4+2] + x[t*4+3];
          s2 += x[t*4+0]*x[t*4+0] + x[t*4+1]*x[t*4+1]
              + x[t*4+2]*x[t*4+2] + x[t*4+3]*x[t*4+3];
        }
        s += __shfl_xor(s, 1);  s2 += __shfl_xor(s2, 1);
        s += __shfl_xor(s, 2);  s2 += __shfl_xor(s2, 2);
        const float mu = s * (1.f / 96.f);
        const float rs = rsqrtf(s2 * (1.f / 96.f) - mu * mu + 1e-5f);
        unsigned int hi[12], lo[12];
#pragma unroll
        for (int t = 0; t < 6; ++t) {
          const float4 g  = *(const float4*)(gw + ch0 + t * 4);
          const float4 be = *(const float4*)(gb + ch0 + t * 4);
          const float y0 = (x[t*4+0] - mu) * rs * g.x + be.x;
          const float y1 = (x[t*4+1] - mu) * rs * g.y + be.y;
          const float y2 = (x[t*4+2] - mu) * rs * g.z + be.z;
          const float y3 = (x[t*4+3] - mu) * rs * g.w + be.w;
          const unsigned int h0 = f2bh(y0), h1 = f2bh(y1), h2 = f2bh(y2), h3 = f2bh(y3);
          hi[t*2+0] = h0 | (h1 << 16);
          hi[t*2+1] = h2 | (h3 << 16);
          if (dstLo) {
            const unsigned int l0 = f2bh(y0 - b2f(h0)), l1 = f2bh(y1 - b2f(h1));
            const unsigned int l2 = f2bh(y2 - b2f(h2)), l3 = f2bh(y3 - b2f(h3));
            lo[t*2+0] = l0 | (l1 << 16);
            lo[t*2+1] = l2 | (l3 << 16);
          }
        }
#pragma unroll
        for (int p = 0; p < 3; ++p) {
          const int off = sw192(tok, (ch0 + p * 8) * 2);
          uint4 uh = {hi[p*4+0], hi[p*4+1], hi[p*4+2], hi[p*4+3]};
          *(uint4*)(dstHi + off) = uh;
          if (dstLo) {
            uint4 ul = {lo[p*4+0], lo[p*4+1], lo[p*4+2], lo[p*4+3]};
            *(uint4*)(dstLo + off) = ul;
          }
        }
      };
      doLN(xa_, nwa, nba, smem + XA_OFF, smem + XLO_OFF);
      doLN(xb_, nwb, nbb, smem + XB_OFF, nullptr);
    } else {
      // zero bytes [28224, 31104): the xa_lo overflow-read zone (NaN guard).
      const int o = 28224 + (tid - 196) * 48;
      const uint4 z = {0u, 0u, 0u, 0u};
      *(uint4*)(smem + o)      = z;
      *(uint4*)(smem + o + 16) = z;
      *(uint4*)(smem + o + 32) = z;
    }
  }
  __syncthreads(); // barA

  // ---------------- Phase B pass 1: K + V (nt = w, w+4, w+8) ---------------
  {
    const float* bias = (const float*)(ws + BIAS_OFF);
    const unsigned char* wqkv = ws + WQKV_OFF;
    const unsigned char* wvlo = ws + WVLO_OFF;

    f32x4 acc[3][4];
#pragma unroll
    for (int i = 0; i < 3; ++i) {
      const int nt = w + 4 * i;
      const float bv = bias[nt * 16 + l15];
      const f32x4 bvv = {bv, bv, bv, bv};
#pragma unroll
      for (int m = 0; m < 4; ++m) acc[i][m] = bvv;
    }

    for (int kt = 0; kt < 3; ++kt) {
      bf16x8 axa[4], axlo[4];
      const int abyte = kt * 64 + lg * 16;
#pragma unroll
      for (int mt = 0; mt < 4; ++mt) {
        const int off = sw192(mt * 16 + l15, abyte);
        axa[mt]  = *(const bf16x8*)(smem + XA_OFF + off);
        axlo[mt] = *(const bf16x8*)(smem + XLO_OFF + off);
      }
#pragma unroll
      for (int i = 0; i < 3; ++i) {
        const int nt = w + 4 * i;
        const bf16x8 bw_ = *(const bf16x8*)(wqkv + ((nt * 3 + kt) * 64 + l) * 16);
        if (nt >= 6) { // v: hi/lo split
          const bf16x8 bl = *(const bf16x8*)(wvlo + (((nt - 6) * 3 + kt) * 64 + l) * 16);
#pragma unroll
          for (int mt = 0; mt < 4; ++mt) {
            acc[i][mt] = __builtin_amdgcn_mfma_f32_16x16x32_bf16(axa[mt],  bw_, acc[i][mt], 0, 0, 0);
            acc[i][mt] = __builtin_amdgcn_mfma_f32_16x16x32_bf16(axlo[mt], bw_, acc[i][mt], 0, 0, 0);
            acc[i][mt] = __builtin_amdgcn_mfma_f32_16x16x32_bf16(axa[mt],  bl,  acc[i][mt], 0, 0, 0);
          }
        } else { // k
#pragma unroll
          for (int mt = 0; mt < 4; ++mt)
            acc[i][mt] = __builtin_amdgcn_mfma_f32_16x16x32_bf16(axa[mt], bw_, acc[i][mt], 0, 0, 0);
        }
      }
    }
    __syncthreads(); // bar1: xa/xa_lo reads done (all waves)

    // K rows -> XA region (predicated row<49; region is 49 rows)
#pragma unroll
    for (int i = 0; i < 2; ++i) {
      const int nt = w + 4 * i;
      if (nt < 6) {
        const int col = nt * 16 + l15;
#pragma unroll
        for (int mt = 0; mt < 4; ++mt)
#pragma unroll
          for (int r = 0; r < 4; ++r) {
            const int row = mt * 16 + lg * 4 + r;
            if (row < 49)
              *(unsigned short*)(smem + XA_OFF + sw192(row, col * 2)) =
                  (unsigned short)f2bh(acc[i][mt][r]);
          }
      }
    }
    // vT -> XLO region (all 96 dims x 64 keys written; garbage keys finite)
#pragma unroll
    for (int i = 1; i < 3; ++i) {
      const int nt = w + 4 * i;
      if (nt >= 6) {
        const int dim = (nt - 6) * 16 + l15;
#pragma unroll
        for (int mt = 0; mt < 4; ++mt) {
          const int key0 = mt * 16 + lg * 4;
          const unsigned int u0 = f2bh(acc[i][mt][0]) | (f2bh(acc[i][mt][1]) << 16);
          const unsigned int u1 = f2bh(acc[i][mt][2]) | (f2bh(acc[i][mt][3]) << 16);
          uint2 u = {u0, u1};
          *(uint2*)(smem + XLO_OFF + ((dim * 128 + key0 * 2) ^ ((dim & 7) << 4))) = u;
        }
      }
    }
  }

  // ---------------- Phase B pass 2: Q (nt = w+12, w+16) --------------------
  {
    const float* bias = (const float*)(ws + BIAS_OFF);
    const unsigned char* wqkv = ws + WQKV_OFF;

    f32x4 acq[2][4];
#pragma unroll
    for (int i = 0; i < 2; ++i) {
      const int nt = w + 12 + 4 * i;
      const float bv = (nt < 18) ? bias[nt * 16 + l15] : 0.f;
      const f32x4 bvv = {bv, bv, bv, bv};
#pragma unroll
      for (int m = 0; m < 4; ++m) acq[i][m] = bvv;
    }

    for (int kt = 0; kt < 3; ++kt) {
      bf16x8 axb[4];
      const int abyte = kt * 64 + lg * 16;
#pragma unroll
      for (int mt = 0; mt < 4; ++mt)
        axb[mt] = *(const bf16x8*)(smem + XB_OFF + sw192(mt * 16 + l15, abyte));
#pragma unroll
      for (int i = 0; i < 2; ++i) {
        const int nt = w + 12 + 4 * i;
        if (nt < 18) {
          const bf16x8 bw_ = *(const bf16x8*)(wqkv + ((nt * 3 + kt) * 64 + l) * 16);
#pragma unroll
          for (int mt = 0; mt < 4; ++mt)
            acq[i][mt] = __builtin_amdgcn_mfma_f32_16x16x32_bf16(axb[mt], bw_, acq[i][mt], 0, 0, 0);
        }
      }
    }
    __syncthreads(); // bar1.5: xb reads done (all waves)

    // Q rows -> XB region (predicated row<49)
#pragma unroll
    for (int i = 0; i < 2; ++i) {
      const int nt = w + 12 + 4 * i;
      if (nt < 18) {
        const int col = (nt - 12) * 16 + l15;
#pragma unroll
        for (int mt = 0; mt < 4; ++mt)
#pragma unroll
          for (int r = 0; r < 4; ++r) {
            const int row = mt * 16 + lg * 4 + r;
            if (row < 49)
              *(unsigned short*)(smem + XB_OFF + sw192(row, col * 2)) =
                  (unsigned short)f2bh(acq[i][mt][r]);
          }
      }
    }
  }
  __syncthreads(); // bar2: K, Q, vT visible (LAST barrier)

  // --------- Phase C+D+E fused: swapped QK^T, in-lane softmax, LDS relayout
  f32x4 po[6];
  {
    const float* bias = (const float*)(ws + BIAS_OFF);
#pragma unroll
    for (int nt = 0; nt < 6; ++nt) {
      const float bv = bias[288 + nt * 16 + l15];
      po[nt] = {bv, bv, bv, bv};
    }

    const unsigned short* rpe = (const unsigned short*)(ws + RPE_OFF);
    const int qrow = w * 16 + l15;
    const int qsz  = (qrow & 7) << 4;

    uint2 rp[3][4];
#pragma unroll
    for (int h = 0; h < 3; ++h)
#pragma unroll
      for (int mt = 0; mt < 4; ++mt)
        rp[h][mt] = *(const uint2*)(rpe + (h * 4096 + qrow * 64 + lg * 16 + mt * 4));

    const unsigned char* wp = ws + WPRJ_OFF;

#pragma unroll
    for (int h = 0; h < 3; ++h) {
      const bf16x8 qB = *(const bf16x8*)(smem + XB_OFF + sw192(qrow, h * 64 + lg * 16));
      f32x4 sT[4];
#pragma unroll
      for (int mt = 0; mt < 4; ++mt) {
        const bf16x8 kA = *(const bf16x8*)(smem + XA_OFF + sw192(mt * 16 + l15, h * 64 + lg * 16));
        sT[mt] = __builtin_amdgcn_mfma_f32_16x16x32_bf16(kA, qB, zf, 0, 0, 0);
      }
      float e[16];
#pragma unroll
      for (int mt = 0; mt < 4; ++mt) {
        const uint2 u = rp[h][mt];
        e[mt*4+0] = sT[mt][0] + b2f(u.x & 0xffffu);
        e[mt*4+1] = sT[mt][1] + b2f(u.x >> 16);
        e[mt*4+2] = sT[mt][2] + b2f(u.y & 0xffffu);
        e[mt*4+3] = sT[mt][3] + b2f(u.y >> 16);
      }
      float mx = e[0];
#pragma unroll
      for (int i = 1; i < 16; ++i) mx = fmaxf(mx, e[i]);
      mx = fmaxf(mx, __shfl_xor(mx, 16));
      mx = fmaxf(mx, __shfl_xor(mx, 32));
      float sm = 0.f;
#pragma unroll
      for (int i = 0; i < 16; ++i) { e[i] = __expf(e[i] - mx); sm += e[i]; }
      sm += __shfl_xor(sm, 16);
      sm += __shfl_xor(sm, 32);
      const float inv = __fdividef(1.f, sm);

      // P^T slice -> PB (wave-local rows)
#pragma unroll
      for (int mt = 0; mt < 4; ++mt) {
        uint2 u;
        u.x = f2bh(e[mt*4+0]) | (f2bh(e[mt*4+1]) << 16);
        u.y = f2bh(e[mt*4+2]) | (f2bh(e[mt*4+3]) << 16);
        *(uint2*)(smem + PB_OFF + ((qrow * 128 + mt * 32 + lg * 8) ^ qsz)) = u;
      }

      // PV
      f32x4 od0 = zf, od1 = zf;
      const int d0 = h * 32 + l15;
      const int d1 = d0 + 16;
#pragma unroll
      for (int blk = 0; blk < 2; ++blk) {
        const bf16x8 pf = *(const bf16x8*)(smem + PB_OFF + ((qrow * 128 + blk * 64 + lg * 16) ^ qsz));
        const bf16x8 v0 = *(const bf16x8*)(smem + XLO_OFF + ((d0 * 128 + blk * 64 + lg * 16) ^ ((d0 & 7) << 4)));
        const bf16x8 v1 = *(const bf16x8*)(smem + XLO_OFF + ((d1 * 128 + blk * 64 + lg * 16) ^ ((d1 & 7) << 4)));
        od0 = __builtin_amdgcn_mfma_f32_16x16x32_bf16(v0, pf, od0, 0, 0, 0);
        od1 = __builtin_amdgcn_mfma_f32_16x16x32_bf16(v1, pf, od1, 0, 0, 0);
      }

      // normalize; O slice -> same buffer (PB consumed for this head)
      {
        uint2 o0p, o1p;
        o0p.x = f2bh(od0[0] * inv) | (f2bh(od0[1] * inv) << 16);
        o0p.y = f2bh(od0[2] * inv) | (f2bh(od0[3] * inv) << 16);
        o1p.x = f2bh(od1[0] * inv) | (f2bh(od1[1] * inv) << 16);
        o1p.y = f2bh(od1[2] * inv) | (f2bh(od1[3] * inv) << 16);
        *(uint2*)(smem + PB_OFF + ((qrow * 128 +      lg * 8) ^ qsz)) = o0p;
        *(uint2*)(smem + PB_OFF + ((qrow * 128 + 32 + lg * 8) ^ qsz)) = o1p;
      }
      const bf16x8 af = *(const bf16x8*)(smem + PB_OFF + ((qrow * 128 + lg * 16) ^ qsz));

      // proj accumulation for kt = h
#pragma unroll
      for (int nt = 0; nt < 6; ++nt) {
        const bf16x8 bp = *(const bf16x8*)(wp + ((nt * 3 + h) * 64 + l) * 16);
        po[nt] = __builtin_amdgcn_mfma_f32_16x16x32_bf16(af, bp, po[nt], 0, 0, 0);
      }
    }
  }

  // ---------------- Epilogue: DIRECT global stores (no barriers) -----------
  {
#pragma unroll
    for (int r = 0; r < 4; ++r) {
      const int row = w * 16 + lg * 4 + r;
      if (row < 49) {
        const int pix = pixbase + (row / 7) * 224 + (row % 7);
        float* dst = out + (long)pix * 96 + l15;
#pragma unroll
        for (int nt = 0; nt < 6; ++nt)
          dst[nt * 16] = po[nt][r];
      }
    }
  }
}

extern "C" void kernel_launch(void* const* d_in, const int* in_sizes, int n_in,
                              void* d_out, int out_size, void* d_ws, size_t ws_size,
                              hipStream_t stream)
{
  const float* rescaled  = (const float*)d_in[0];
  const float* rescaler  = (const float*)d_in[1];
  const float* norm_w_a  = (const float*)d_in[2];
  const float* norm_b_a  = (const float*)d_in[3];
  const float* norm_w_b  = (const float*)d_in[4];
  const float* norm_b_b  = (const float*)d_in[5];
  const float* qkv_w_a   = (const float*)d_in[6];
  const float* qkv_b_a   = (const float*)d_in[7];
  const float* qkv_w_b   = (const float*)d_in[8];
  const float* qkv_b_b   = (const float*)d_in[9];
  const float* rpe_table = (const float*)d_in[10];
  const float* proj_w    = (const float*)d_in[11];
  const float* proj_b    = (const float*)d_in[12];
  const int*   rpe_index = (const int*)d_in[13];
  unsigned char* ws = (unsigned char*)d_ws;
  float* outp = (float*)d_out;

  hipLaunchKernelGGL(prepack_kernel, dim3(64), dim3(256), 0, stream,
                     qkv_w_a, qkv_b_a, qkv_w_b, qkv_b_b, rpe_table, proj_w,
                     proj_b, rpe_index, ws);
  hipLaunchKernelGGL(swin_main, dim3(8192), dim3(256), 0, stream,
                     rescaled, rescaler, norm_w_a, norm_b_a, norm_w_b, norm_b_b,
                     ws, outp);
}